// Round 7
// baseline (314.015 us; speedup 1.0000x reference)
//
#include <hip/hip_runtime.h>
#include <hip/hip_bf16.h>

typedef __attribute__((ext_vector_type(8))) __bf16 bf16x8;
typedef __attribute__((ext_vector_type(4))) float f32x4;
typedef __attribute__((ext_vector_type(16))) float f32x16;

#define DEV static __device__ __forceinline__

DEV unsigned short f2bf(float f) {
  __bf16 h = (__bf16)f;
  union { __bf16 h; unsigned short u; } v; v.h = h;
  return v.u;
}
DEV float bf2f(unsigned short h) {
  union { unsigned int u; float f; } v; v.u = ((unsigned int)h) << 16;
  return v.f;
}
DEV unsigned pkbf(float lo, float hi) {
  union { __bf16 h[2]; unsigned u; } v;
  v.h[0] = (__bf16)lo; v.h[1] = (__bf16)hi;
  return v.u;
}
DEV f32x4 mfma16(bf16x8 a, bf16x8 b, f32x4 c) {
  return __builtin_amdgcn_mfma_f32_16x16x32_bf16(a, b, c, 0, 0, 0);
}
DEV f32x16 mfma32(bf16x8 a, bf16x8 b, f32x16 c) {
  return __builtin_amdgcn_mfma_f32_32x32x16_bf16(a, b, c, 0, 0, 0);
}
DEV void gload_lds16(const void* g, void* l) {
  __builtin_amdgcn_global_load_lds((__attribute__((address_space(1))) void*)g,
                                   (__attribute__((address_space(3))) void*)l,
                                   16, 0, 0);
}
DEV float fexp2(float x) { return exp2f(x); }

// ---------------- fused f32 -> bf16 convert of all 7 weights ----------------
struct CvtArgs { const float* src[7]; int cum[8]; };
__global__ __launch_bounds__(256) void cvt_all(CvtArgs a, unsigned short* __restrict__ dst) {
  int i = (blockIdx.x * 256 + threadIdx.x) * 4;
  if (i >= a.cum[7]) return;
  int w = 0;
#pragma unroll 7
  for (int t = 0; t < 7; ++t) if (i >= a.cum[t + 1]) w = t + 1;
  float4 v = *(const float4*)(a.src[w] + (i - a.cum[w]));
  dst[i + 0] = f2bf(v.x);
  dst[i + 1] = f2bf(v.y);
  dst[i + 2] = f2bf(v.z);
  dst[i + 3] = f2bf(v.w);
}

// ---------------- RMSNorm: fp32 in -> bf16 out (D=1024) ----------------
__global__ __launch_bounds__(256) void rmsnorm_k(const float* __restrict__ x,
                                                 const float* __restrict__ w,
                                                 unsigned short* __restrict__ out) {
  int row = blockIdx.x;
  int tid = threadIdx.x;
  const float* xr = x + (size_t)row * 1024;
  float4 v = *(const float4*)(xr + tid * 4);
  float ss = v.x * v.x + v.y * v.y + v.z * v.z + v.w * v.w;
#pragma unroll
  for (int m = 32; m >= 1; m >>= 1) ss += __shfl_xor(ss, m);
  __shared__ float red[4];
  int wid = tid >> 6;
  if ((tid & 63) == 0) red[wid] = ss;
  __syncthreads();
  float tot = red[0] + red[1] + red[2] + red[3];
  float rs = rsqrtf(tot * (1.0f / 1024.0f) + 1e-5f);
  float4 wv = *(const float4*)(w + tid * 4);
  unsigned short* o = out + (size_t)row * 1024 + tid * 4;
  o[0] = f2bf(v.x * rs * wv.x);
  o[1] = f2bf(v.y * rs * wv.y);
  o[2] = f2bf(v.z * rs * wv.z);
  o[3] = f2bf(v.w * rs * wv.w);
}

// ---------------- RoPE in-place on q and k, [BH=32][S=2048][64] bf16 ----------------
__global__ __launch_bounds__(256) void rope2_k(unsigned short* __restrict__ q,
                                               unsigned short* __restrict__ k,
                                               const int* __restrict__ pos) {
  int gid = blockIdx.x * 256 + threadIdx.x;
  unsigned short* x = (gid < 2097152) ? q : k;
  int idx = gid & 2097151;
  int i = idx & 31;
  int s = (idx >> 5) & 2047;
  int bh = idx >> 16;
  int b = bh >> 4;
  float p = (float)pos[b * 2048 + s];
  float inv = exp2f(-(float)i * 0.4152410118609203f);
  float ang = p * inv;
  float sn = sinf(ang), cs = cosf(ang);
  size_t base = (((size_t)bh * 2048) + s) * 64 + 2 * i;
  float x1 = bf2f(x[base]), x2 = bf2f(x[base + 1]);
  x[base]     = f2bf(x1 * cs - x2 * sn);
  x[base + 1] = f2bf(x1 * sn + x2 * cs);
}

// ================= 256x256 8-phase GEMM =================
template <int MODE>
DEV void gemm8_body(const unsigned short* __restrict__ A, int lda,
                    const unsigned short* __restrict__ B, int ldb,
                    int bm, int bn, int kbase, int nt,
                    unsigned short* __restrict__ outb, float* __restrict__ outf,
                    const float* __restrict__ resid, const unsigned short* __restrict__ gate,
                    unsigned short* As, unsigned short* Bs) {
  const int tid = threadIdx.x;
  const int lane = tid & 63, wid = tid >> 6;
  const int wr = wid >> 2, wc = wid & 3;
  const int m0 = bm * 256, n0 = bn * 256;

  const int r0 = tid >> 2, r1 = 128 + (tid >> 2), cc = tid & 3;
  const int sc0 = (cc ^ ((r0 >> 1) & 3)) * 8;
  const int sc1 = (cc ^ ((r1 >> 1) & 3)) * 8;
  const size_t arow0 = (size_t)(m0 + r0) * lda, arow1 = (size_t)(m0 + r1) * lda;
  const size_t brow0 = (size_t)(n0 + r0) * ldb, brow1 = (size_t)(n0 + r1) * ldb;
  const int du0 = tid * 8, du1 = (512 + tid) * 8;

  auto stA = [&](int t, int kh) {
    unsigned short* d = As + ((((t & 1) << 1) | kh) * 8192);
    const unsigned short* s = A + kbase + t * 64 + kh * 32;
    gload_lds16(s + arow0 + sc0, d + du0);
    gload_lds16(s + arow1 + sc1, d + du1);
  };
  auto stB = [&](int t, int kh) {
    unsigned short* d = Bs + ((((t & 1) << 1) | kh) * 8192);
    const unsigned short* s = B + kbase + t * 64 + kh * 32;
    gload_lds16(s + brow0 + sc0, d + du0);
    gload_lds16(s + brow1 + sc1, d + du1);
  };

  const int fcol = ((lane >> 4) ^ ((lane >> 1) & 3)) * 8;
  const int frow = lane & 15;
  const int abase = (wr * 128 + frow) * 32 + fcol;
  const int bbase = (wc * 64 + frow) * 32 + fcol;

  f32x4 acc[8][4] = {};
  bf16x8 a[4], b[4];

#define LOADA(buf, ks, mh) { const unsigned short* p_ = As + (((buf) << 1) | (ks)) * 8192 + abase + (mh) * 2048; \
  a[0] = *(const bf16x8*)(p_); a[1] = *(const bf16x8*)(p_ + 512); \
  a[2] = *(const bf16x8*)(p_ + 1024); a[3] = *(const bf16x8*)(p_ + 1536); }
#define LOADB(buf, ks) { const unsigned short* p_ = Bs + (((buf) << 1) | (ks)) * 8192 + bbase; \
  b[0] = *(const bf16x8*)(p_); b[1] = *(const bf16x8*)(p_ + 512); \
  b[2] = *(const bf16x8*)(p_ + 1024); b[3] = *(const bf16x8*)(p_ + 1536); }
#define MFMAQ(mh) { _Pragma("unroll") for (int fi = 0; fi < 4; ++fi) \
  _Pragma("unroll") for (int j = 0; j < 4; ++j) \
    acc[(mh) * 4 + fi][j] = mfma16(a[fi], b[j], acc[(mh) * 4 + fi][j]); }
#define LGK0() { asm volatile("s_waitcnt lgkmcnt(0)" ::: "memory"); __builtin_amdgcn_sched_barrier(0); }

  stA(0, 0); stB(0, 0); stA(0, 1); stB(0, 1);
  stA(1, 0); stB(1, 0);
  asm volatile("s_waitcnt vmcnt(4)" ::: "memory");
  __builtin_amdgcn_s_barrier();

  for (int t = 0; t < nt; ++t) {
    const int buf = t & 1;
    LOADA(buf, 0, 0); LOADB(buf, 0);
    if (t + 1 < nt) stA(t + 1, 1);
    __builtin_amdgcn_s_barrier();
    LGK0();
    __builtin_amdgcn_s_setprio(1); MFMAQ(0); __builtin_amdgcn_s_setprio(0);
    __builtin_amdgcn_s_barrier();
    LOADA(buf, 0, 1);
    if (t + 1 < nt) stB(t + 1, 1);
    __builtin_amdgcn_s_barrier();
    LGK0();
    __builtin_amdgcn_s_setprio(1); MFMAQ(1); __builtin_amdgcn_s_setprio(0);
    __builtin_amdgcn_s_barrier();
    LOADA(buf, 1, 0); LOADB(buf, 1);
    if (t + 2 < nt) stA(t + 2, 0);
    __builtin_amdgcn_s_barrier();
    LGK0();
    __builtin_amdgcn_s_setprio(1); MFMAQ(0); __builtin_amdgcn_s_setprio(0);
    __builtin_amdgcn_s_barrier();
    LOADA(buf, 1, 1);
    if (t + 2 < nt) stB(t + 2, 0);
    __builtin_amdgcn_s_barrier();
    LGK0();
    __builtin_amdgcn_s_setprio(1); MFMAQ(1); __builtin_amdgcn_s_setprio(0);
    if (t + 1 < nt) {
      if (t + 2 < nt) { asm volatile("s_waitcnt vmcnt(4)" ::: "memory"); }
      else            { asm volatile("s_waitcnt vmcnt(0)" ::: "memory"); }
      __builtin_amdgcn_s_barrier();
    }
  }
#undef LOADA
#undef LOADB
#undef MFMAQ
#undef LGK0

#pragma unroll
  for (int i = 0; i < 8; ++i)
#pragma unroll
    for (int j = 0; j < 4; ++j)
#pragma unroll
      for (int r = 0; r < 4; ++r) {
        int m = m0 + wr * 128 + i * 16 + ((lane >> 4) << 2) + r;
        int n = n0 + wc * 64 + j * 16 + (lane & 15);
        float v = acc[i][j][r];
        if (MODE == 0) {
          unsigned short* dst = outb + ((n >= 1024) ? 4194304 : 0);
          int nn = n & 1023;
          int bb = m >> 11, s = m & 2047, hh = nn >> 6, dd = nn & 63;
          dst[(((size_t)bb * 16 + hh) * 2048 + s) * 64 + dd] = f2bf(v);
        } else if (MODE == 1) {
          int hh = m >> 6, dd = m & 63, bb = n >> 11, s = n & 2047;
          outb[(((size_t)bb * 16 + hh) * 64 + dd) * 2048 + s] = f2bf(v);
        } else if (MODE == 2) {
          size_t idx = (size_t)m * 1024 + n;
          outf[idx] = resid[idx] + v;
        } else if (MODE == 3) {
          outb[(size_t)m * 4096 + n] = f2bf(v);
        } else if (MODE == 4) {
          size_t idx = (size_t)m * 4096 + n;
          float g = bf2f(gate[idx]);
          outb[idx] = f2bf(g / (1.0f + __expf(-g)) * v);
        } else {
          outf[(size_t)m * 1024 + n] = v;
        }
      }
}

DEV void swz_map(int bid, int nwg, int MT, int& bm, int& bn) {
  int cpx = nwg >> 3;
  int sw = (bid & 7) * cpx + (bid >> 3);
  bm = sw % MT;
  bn = sw / MT;
}

template <int MODE>
__global__ __launch_bounds__(512, 2) void gemm8_k(const unsigned short* __restrict__ A, int lda,
                                                  const unsigned short* __restrict__ B, int ldb,
                                                  int MT, int kz, int nt,
                                                  unsigned short* __restrict__ outb,
                                                  float* __restrict__ outf,
                                                  const float* __restrict__ resid,
                                                  const unsigned short* __restrict__ gate) {
  __shared__ __align__(16) unsigned short lds[65536];
  int bm, bn;
  swz_map(blockIdx.x, gridDim.x, MT, bm, bn);
  int kb = kz * blockIdx.y;
  float* of = outf;
  if (MODE == 5) of += (size_t)blockIdx.y * 4194304;
  gemm8_body<MODE>(A, lda, B, ldb, bm, bn, kb, nt, outb, of, resid, gate, lds, lds + 32768);
}

__global__ __launch_bounds__(512, 2) void gemm8_qkv(const unsigned short* __restrict__ xn,
                                                    const unsigned short* __restrict__ wqk,
                                                    const unsigned short* __restrict__ wv,
                                                    unsigned short* __restrict__ qk_out,
                                                    unsigned short* __restrict__ vt_out) {
  __shared__ __align__(16) unsigned short lds[65536];
  int bid = blockIdx.x;
  if (bid < 128) {
    int bm, bn;
    swz_map(bid, 128, 16, bm, bn);
    gemm8_body<0>(xn, 1024, wqk, 1024, bm, bn, 0, 16, qk_out, nullptr, nullptr, nullptr, lds, lds + 32768);
  } else {
    bid -= 128;
    int bm, bn;
    swz_map(bid, 64, 4, bm, bn);
    gemm8_body<1>(wv, 1024, xn, 1024, bm, bn, 0, 16, vt_out, nullptr, nullptr, nullptr, lds, lds + 32768);
  }
}

// ---------------- 128x128 2-phase GEMM for wo ----------------
__global__ __launch_bounds__(256) void gemm_wo(const unsigned short* __restrict__ A,
                                               const unsigned short* __restrict__ Bw,
                                               float* __restrict__ outf,
                                               const float* __restrict__ resid) {
  __shared__ __align__(16) unsigned short As[128 * 64];
  __shared__ __align__(16) unsigned short Bs[128 * 64];
  const int K = 1024, N = 1024;
  const int tid = threadIdx.x;
  const int wid = tid >> 6, lane = tid & 63;
  const int wr = wid >> 1, wc = wid & 1;
  const int m0 = blockIdx.x * 128, n0 = blockIdx.y * 128;
  const int sw = (lane & 7) * 8;
  f32x4 acc[4][4] = {};

  for (int k0 = 0; k0 < K; k0 += 64) {
    __syncthreads();
#pragma unroll
    for (int it = 0; it < 4; ++it) {
      int c = wid * 4 + it;
      int row = c * 8 + (lane >> 3);
      int col = ((lane & 7) ^ (row & 7)) * 8;
      gload_lds16(A + (size_t)(m0 + row) * K + k0 + col, As + c * 512);
      gload_lds16(Bw + (size_t)(n0 + row) * K + k0 + col, Bs + c * 512);
    }
    asm volatile("s_waitcnt vmcnt(0)" ::: "memory");
    __syncthreads();
#pragma unroll
    for (int kk = 0; kk < 2; ++kk) {
      const int kof = (kk * 32 + (lane >> 4) * 8) ^ sw;
      bf16x8 af[4], bfr[4];
#pragma unroll
      for (int i = 0; i < 4; ++i) {
        af[i]  = *(const bf16x8*)(As + (wr * 64 + i * 16 + (lane & 15)) * 64 + kof);
        bfr[i] = *(const bf16x8*)(Bs + (wc * 64 + i * 16 + (lane & 15)) * 64 + kof);
      }
#pragma unroll
      for (int i = 0; i < 4; ++i)
#pragma unroll
        for (int j = 0; j < 4; ++j) acc[i][j] = mfma16(af[i], bfr[j], acc[i][j]);
    }
  }
  const int rb = m0 + wr * 64 + ((lane >> 4) * 4);
  const int cb = n0 + wc * 64 + (lane & 15);
#pragma unroll
  for (int i = 0; i < 4; ++i)
#pragma unroll
    for (int r = 0; r < 4; ++r) {
      int m = rb + i * 16 + r;
#pragma unroll
      for (int j = 0; j < 4; ++j) {
        size_t idx = (size_t)m * N + cb + j * 16;
        outf[idx] = resid[idx] + acc[i][j][r];
      }
    }
}

// ---------------- w2 split-K reduce ----------------
__global__ __launch_bounds__(256) void reduce_k(float* __restrict__ out,
                                                const float* __restrict__ part) {
  int i = (blockIdx.x * 256 + threadIdx.x) * 4;
  float4 o = *(const float4*)(out + i);
  float4 p0 = *(const float4*)(part + i);
  float4 p1 = *(const float4*)(part + 4194304 + i);
  float4 p2 = *(const float4*)(part + 8388608 + i);
  float4 p3 = *(const float4*)(part + 12582912 + i);
  o.x += p0.x + p1.x + p2.x + p3.x;
  o.y += p0.y + p1.y + p2.y + p3.y;
  o.z += p0.z + p1.z + p2.z + p3.z;
  o.w += p0.w + p1.w + p2.w + p3.w;
  *(float4*)(out + i) = o;
}

// ---------------- Flash attention: swapped-QK 32x32, 8 waves, in-block KV-split ----------------
// q,k: [BH][S][64]; vt: V^T [BH][64][S]; ctx: [B][S][1024]
// 512 blocks x 512 thr. Waves 0-3 (group 0): KV tiles [0, t+1); waves 4-7 (group 1):
// tiles [t+1, 2t+2). Equal iteration counts -> block-wide barriers stay in lockstep.
// End: group1 publishes (m,l,O) via LDS (aliased over dead staging bufs), group0 merges.
__global__ __launch_bounds__(512, 4) void attn_k(const unsigned short* __restrict__ q,
                                                 const unsigned short* __restrict__ k,
                                                 const unsigned short* __restrict__ vt,
                                                 unsigned short* __restrict__ ctx) {
  __shared__ __align__(16) unsigned short Ks[16384];   // [g][buf][4096]
  __shared__ __align__(16) unsigned short Vs[16384];
  const int bid = blockIdx.x;                        // 512 blocks
  const int xcd = bid & 7, inner = bid >> 3;         // XCD-pinned: 4 heads per XCD
  const int bh = xcd * 4 + (inner & 3);
  const int qtile = 15 - (inner >> 2);               // longest first
  const int tid = threadIdx.x, wid = tid >> 6, lane = tid & 63;
  const int w4 = wid & 3, g = wid >> 2;
  const int l31 = lane & 31, hi = lane >> 5;
  const size_t bhS = (size_t)bh * 2048;
  const size_t bhD = (size_t)bh * 64 * 2048;
  const int b = bh >> 4, hh = bh & 15;
  const float SC2 = 0.18033688011112042f;  // 0.125 * log2(e)

  const int NT = qtile + 1;                // tiles per group
  const int kb = g * NT;                   // group's first global kv tile

  // staging: group's 4 waves each stage 2 K-chunks + 2 V-chunks of 512 u16
  const int c0 = w4 * 2, c1 = c0 + 1;
  const int rl0 = c0 * 4 + (lane >> 4), rl1 = c1 * 4 + (lane >> 4);
  const int u0 = ((lane & 15) ^ (rl0 & 15)) * 8;
  const int u1 = ((lane & 15) ^ (rl1 & 15)) * 8;
  const int sr0 = rl0 + ((u0 >> 6) << 5), scol0 = u0 & 63;
  const int sr1 = rl1 + ((u1 >> 6) << 5), scol1 = u1 & 63;
  unsigned short* KsG = Ks + g * 8192;
  unsigned short* VsG = Vs + g * 8192;

  auto stage = [&](int ktl, int buf) {
    int kt = kb + ktl;
    gload_lds16(k + (bhS + kt * 64 + sr0) * 64 + scol0, KsG + buf * 4096 + c0 * 512);
    gload_lds16(k + (bhS + kt * 64 + sr1) * 64 + scol1, KsG + buf * 4096 + c1 * 512);
    gload_lds16(vt + bhD + (size_t)sr0 * 2048 + kt * 64 + scol0, VsG + buf * 4096 + c0 * 512);
    gload_lds16(vt + bhD + (size_t)sr1 * 2048 + kt * 64 + scol1, VsG + buf * 4096 + c1 * 512);
  };

  // Q fragments (B-operand): col=l31=q-row; pre-scaled by SC2
  const int qrow = qtile * 128 + w4 * 32 + l31;
  bf16x8 qf[4];
  {
    const unsigned short* qp = q + (bhS + qrow) * 64 + hi * 8;
#pragma unroll
    for (int c = 0; c < 4; ++c) {
      bf16x8 t = *(const bf16x8*)(qp + c * 16);
#pragma unroll
      for (int j = 0; j < 8; ++j) t[j] = (__bf16)((float)t[j] * SC2);
      qf[c] = t;
    }
  }

  float mrow = -1e30f, lrow = 0.0f;
  f32x16 o0 = {}, o1 = {};
  const int qw0 = qtile * 128 + w4 * 32;
  const int rsw = (l31 & 15) * 8;

  stage(0, 0);
  stage(1, 1);
  asm volatile("s_waitcnt vmcnt(4)" ::: "memory");
  __builtin_amdgcn_s_barrier();

  for (int ktl = 0; ktl < NT; ++ktl) {
    const int cur = ktl & 1;
    const int kt = kb + ktl;
    // ---- QK^T swapped: S = mfma32(K, Q); lane holds S[keys][q=l31]
    f32x16 sa0 = {}, sa1 = {};
#pragma unroll
    for (int c = 0; c < 4; ++c) {
      int colbase = c * 16 + hi * 8;
      bf16x8 k0 = *(const bf16x8*)(&KsG[cur * 4096 + l31 * 128 + (colbase ^ rsw)]);
      bf16x8 k1 = *(const bf16x8*)(&KsG[cur * 4096 + l31 * 128 + ((64 + colbase) ^ rsw)]);
      sa0 = mfma32(k0, qf[c], sa0);
      sa1 = mfma32(k1, qf[c], sa1);
    }
    float s[32];
#pragma unroll
    for (int r = 0; r < 16; ++r) { s[r] = sa0[r]; s[16 + r] = sa1[r]; }
    // ---- causal mask (near-diagonal tiles only)
    if (kt * 64 + 63 > qw0) {
      const int qg = qw0 + l31;
#pragma unroll
      for (int r = 0; r < 16; ++r) {
        int key0 = kt * 64 + (r & 3) + 8 * (r >> 2) + 4 * hi;
        if (key0 > qg) s[r] = -3e38f;
        if (key0 + 32 > qg) s[16 + r] = -3e38f;
      }
    }
    // ---- lane-local row max + single cross-half merge
    float pmax = s[0];
#pragma unroll
    for (int r = 1; r < 32; ++r) pmax = fmaxf(pmax, s[r]);
    pmax = fmaxf(pmax, __shfl_xor(pmax, 32));
    // ---- defer-max rescale (rare)
    if (!__all(pmax <= mrow + 11.5f)) {
      float mnew = fmaxf(mrow, pmax);
      float dl = mrow - mnew;
      mrow = mnew;
      lrow *= fexp2(dl);
#pragma unroll
      for (int r = 0; r < 16; ++r) {
        int qsrc = (r & 3) + 8 * (r >> 2) + 4 * hi;
        float ar = fexp2(__shfl(dl, qsrc, 64));
        o0[r] *= ar; o1[r] *= ar;
      }
    }
    // ---- P = exp2(S - m), lane-local sum
    float sum = 0.0f;
#pragma unroll
    for (int r = 0; r < 32; ++r) { s[r] = fexp2(s[r] - mrow); sum += s[r]; }
    lrow += sum;
    // ---- pack to bf16 pairs + permlane32_swap into PV A-frags
    unsigned pw[16];
#pragma unroll
    for (int i = 0; i < 16; ++i) pw[i] = pkbf(s[2 * i], s[2 * i + 1]);
#pragma unroll
    for (int gg = 0; gg < 4; ++gg) {
      asm volatile("v_permlane32_swap_b32 %0, %1" : "+v"(pw[4 * gg]), "+v"(pw[4 * gg + 2]));
      asm volatile("v_permlane32_swap_b32 %0, %1" : "+v"(pw[4 * gg + 1]), "+v"(pw[4 * gg + 3]));
    }
    // ---- PV: O += P * V
#pragma unroll
    for (int gg = 0; gg < 4; ++gg) {
      union { unsigned w[4]; bf16x8 v; } pa;
      pa.w[0] = pw[4 * gg]; pa.w[1] = pw[4 * gg + 1];
      pa.w[2] = pw[4 * gg + 2]; pa.w[3] = pw[4 * gg + 3];
      int kl = gg * 16 + hi * 8;
      bf16x8 v0 = *(const bf16x8*)(&VsG[cur * 4096 + l31 * 128 + (kl ^ rsw)]);
      bf16x8 v1 = *(const bf16x8*)(&VsG[cur * 4096 + l31 * 128 + ((64 + kl) ^ rsw)]);
      o0 = mfma32(pa.v, v0, o0);
      o1 = mfma32(pa.v, v1, o1);
    }
    __builtin_amdgcn_s_barrier();
    if (ktl + 2 < NT) {
      stage(ktl + 2, cur);
      asm volatile("s_waitcnt vmcnt(4)" ::: "memory");
    } else if (ktl + 1 < NT) {
      asm volatile("s_waitcnt vmcnt(0)" ::: "memory");
    }
    __builtin_amdgcn_s_barrier();
  }

  // merge lrow halves within wave
  lrow += __shfl_xor(lrow, 32);

  // drain stray prefetch loads into staging LDS before aliasing it
  asm volatile("s_waitcnt vmcnt(0)" ::: "memory");
  __builtin_amdgcn_s_barrier();

  // aliased publish buffers (staging is dead now)
  unsigned* Obw = (unsigned*)Ks;            // [4 pairs][64 lanes][16 dwords]
  float* mlp = (float*)Vs;                  // [4 pairs][32 rows][2]

  if (g == 1) {
    int ob = (w4 * 64 + lane) * 16;
    unsigned tmp[16];
#pragma unroll
    for (int i = 0; i < 8; ++i) tmp[i] = pkbf(o0[2 * i], o0[2 * i + 1]);
#pragma unroll
    for (int i = 0; i < 8; ++i) tmp[8 + i] = pkbf(o1[2 * i], o1[2 * i + 1]);
#pragma unroll
    for (int c = 0; c < 4; ++c)
      *(uint4*)(&Obw[ob + 4 * c]) = make_uint4(tmp[4 * c], tmp[4 * c + 1], tmp[4 * c + 2], tmp[4 * c + 3]);
    if (hi == 0) {
      mlp[(w4 * 32 + l31) * 2]     = mrow;
      mlp[(w4 * 32 + l31) * 2 + 1] = lrow;
    }
  }
  __builtin_amdgcn_s_barrier();

  if (g == 0) {
    float m1 = mlp[(w4 * 32 + l31) * 2];
    float l1 = mlp[(w4 * 32 + l31) * 2 + 1];
    float mF = fmaxf(mrow, m1);
    float a0 = fexp2(mrow - mF);
    float a1 = fexp2(m1 - mF);
    float lF = lrow * a0 + l1 * a1;
    float inv = 1.0f / lF;
    int ob = (w4 * 64 + lane) * 16;
    unsigned od[16];
#pragma unroll
    for (int c = 0; c < 4; ++c) {
      uint4 t = *(const uint4*)(&Obw[ob + 4 * c]);
      od[4 * c] = t.x; od[4 * c + 1] = t.y; od[4 * c + 2] = t.z; od[4 * c + 3] = t.w;
    }
#pragma unroll
    for (int r = 0; r < 16; ++r) {
      int qsrc = (r & 3) + 8 * (r >> 2) + 4 * hi;
      float a0r = __shfl(a0, qsrc, 64);
      float a1r = __shfl(a1, qsrc, 64);
      float invr = __shfl(inv, qsrc, 64);
      float ob0 = bf2f((unsigned short)((od[r >> 1] >> ((r & 1) * 16)) & 0xffff));
      float ob1 = bf2f((unsigned short)((od[8 + (r >> 1)] >> ((r & 1) * 16)) & 0xffff));
      float v0 = (o0[r] * a0r + ob0 * a1r) * invr;
      float v1 = (o1[r] * a0r + ob1 * a1r) * invr;
      int srow = qtile * 128 + w4 * 32 + qsrc;
      size_t base = ((size_t)b * 2048 + srow) * 1024 + hh * 64 + l31;
      ctx[base]      = f2bf(v0);
      ctx[base + 32] = f2bf(v1);
    }
  }
}

extern "C" void kernel_launch(void* const* d_in, const int* in_sizes, int n_in,
                              void* d_out, int out_size, void* d_ws, size_t ws_size,
                              hipStream_t stream) {
  (void)in_sizes; (void)n_in; (void)out_size; (void)ws_size;
  const float* in_f = (const float*)d_in[0];
  const int* pos    = (const int*)d_in[1];
  const float* q_w  = (const float*)d_in[2];
  const float* k_w  = (const float*)d_in[3];
  const float* v_w  = (const float*)d_in[4];
  const float* o_w  = (const float*)d_in[5];
  const float* ln1  = (const float*)d_in[6];
  const float* ln2  = (const float*)d_in[7];
  const float* w1   = (const float*)d_in[8];
  const float* w2   = (const float*)d_in[9];
  const float* w3   = (const float*)d_in[10];
  float* out = (float*)d_out;

  unsigned short* ws = (unsigned short*)d_ws;
  unsigned short* wb   = ws;
  unsigned short* wqkb = wb;
  unsigned short* wvb  = wb + 2097152;
  unsigned short* wob  = wb + 3145728;
  unsigned short* w1b  = wb + 4194304;
  unsigned short* w2b  = wb + 8388608;
  unsigned short* w3b  = wb + 12582912;
  unsigned short* xn   = ws + 16777216;
  unsigned short* qb   = ws + 20971520;
  unsigned short* kb   = ws + 25165824;   // must be qb + 4194304
  unsigned short* vb   = ws + 29360128;   // V^T [bh][64][2048]
  unsigned short* cx   = ws + 33554432;
  unsigned short* gb   = ws + 37748736;
  float* part          = (float*)(ws + 20971520);  // aliases qb..gb (dead by w2)
  unsigned short* hb   = ws + 54525952;

  CvtArgs ca;
  ca.src[0] = q_w; ca.src[1] = k_w; ca.src[2] = v_w; ca.src[3] = o_w;
  ca.src[4] = w1;  ca.src[5] = w2;  ca.src[6] = w3;
  ca.cum[0] = 0;        ca.cum[1] = 1048576;  ca.cum[2] = 2097152;  ca.cum[3] = 3145728;
  ca.cum[4] = 4194304;  ca.cum[5] = 8388608;  ca.cum[6] = 12582912; ca.cum[7] = 16777216;
  cvt_all<<<16384, 256, 0, stream>>>(ca, wb);

  rmsnorm_k<<<4096, 256, 0, stream>>>(in_f, ln1, xn);

  gemm8_qkv<<<192, 512, 0, stream>>>(xn, wqkb, wvb, qb, vb);

  rope2_k<<<16384, 256, 0, stream>>>(qb, kb, pos);

  attn_k<<<512, 512, 0, stream>>>(qb, kb, vb, cx);

  gemm_wo<<<dim3(32, 8), 256, 0, stream>>>(cx, wob, out, in_f);

  rmsnorm_k<<<4096, 256, 0, stream>>>(out, ln2, xn);

  gemm8_k<3><<<256, 512, 0, stream>>>(xn, 1024, w1b, 1024, 16, 0, 16, gb, nullptr, nullptr, nullptr);
  gemm8_k<4><<<256, 512, 0, stream>>>(xn, 1024, w3b, 1024, 16, 0, 16, hb, nullptr, nullptr, gb);
  gemm8_k<5><<<dim3(64, 4), 512, 0, stream>>>(hb, 4096, w2b, 4096, 16, 1024, 16, nullptr, part, nullptr, nullptr);

  reduce_k<<<4096, 256, 0, stream>>>(out, part);
}

// Round 8
// 294.070 us; speedup vs baseline: 1.0678x; 1.0678x over previous
//
#include <hip/hip_runtime.h>
#include <hip/hip_bf16.h>

typedef __attribute__((ext_vector_type(8))) __bf16 bf16x8;
typedef __attribute__((ext_vector_type(4))) float f32x4;

#define DEV static __device__ __forceinline__

DEV unsigned short f2bf(float f) {
  __bf16 h = (__bf16)f;
  union { __bf16 h; unsigned short u; } v; v.h = h;
  return v.u;
}
DEV float bf2f(unsigned short h) {
  union { unsigned int u; float f; } v; v.u = ((unsigned int)h) << 16;
  return v.f;
}
DEV unsigned pkbf(float lo, float hi) {
  union { __bf16 h[2]; unsigned u; } v;
  v.h[0] = (__bf16)lo; v.h[1] = (__bf16)hi;
  return v.u;
}
DEV f32x4 mfma16(bf16x8 a, bf16x8 b, f32x4 c) {
  return __builtin_amdgcn_mfma_f32_16x16x32_bf16(a, b, c, 0, 0, 0);
}
DEV void gload_lds16(const void* g, void* l) {
  __builtin_amdgcn_global_load_lds((__attribute__((address_space(1))) void*)g,
                                   (__attribute__((address_space(3))) void*)l,
                                   16, 0, 0);
}
DEV float fexp2(float x) { return exp2f(x); }

// ---------------- fused f32 -> bf16 convert of all 7 weights ----------------
struct CvtArgs { const float* src[7]; int cum[8]; };
__global__ __launch_bounds__(256) void cvt_all(CvtArgs a, unsigned short* __restrict__ dst) {
  int i = (blockIdx.x * 256 + threadIdx.x) * 4;
  if (i >= a.cum[7]) return;
  int w = 0;
#pragma unroll 7
  for (int t = 0; t < 7; ++t) if (i >= a.cum[t + 1]) w = t + 1;
  float4 v = *(const float4*)(a.src[w] + (i - a.cum[w]));
  dst[i + 0] = f2bf(v.x);
  dst[i + 1] = f2bf(v.y);
  dst[i + 2] = f2bf(v.z);
  dst[i + 3] = f2bf(v.w);
}

// ---------------- RMSNorm: fp32 in -> bf16 out (D=1024) ----------------
__global__ __launch_bounds__(256) void rmsnorm_k(const float* __restrict__ x,
                                                 const float* __restrict__ w,
                                                 unsigned short* __restrict__ out) {
  int row = blockIdx.x;
  int tid = threadIdx.x;
  const float* xr = x + (size_t)row * 1024;
  float4 v = *(const float4*)(xr + tid * 4);
  float ss = v.x * v.x + v.y * v.y + v.z * v.z + v.w * v.w;
#pragma unroll
  for (int m = 32; m >= 1; m >>= 1) ss += __shfl_xor(ss, m);
  __shared__ float red[4];
  int wid = tid >> 6;
  if ((tid & 63) == 0) red[wid] = ss;
  __syncthreads();
  float tot = red[0] + red[1] + red[2] + red[3];
  float rs = rsqrtf(tot * (1.0f / 1024.0f) + 1e-5f);
  float4 wv = *(const float4*)(w + tid * 4);
  unsigned short* o = out + (size_t)row * 1024 + tid * 4;
  o[0] = f2bf(v.x * rs * wv.x);
  o[1] = f2bf(v.y * rs * wv.y);
  o[2] = f2bf(v.z * rs * wv.z);
  o[3] = f2bf(v.w * rs * wv.w);
}

// ---------------- RoPE in-place: one thread rotates q AND k ----------------
__global__ __launch_bounds__(256) void rope2_k(unsigned short* __restrict__ q,
                                               unsigned short* __restrict__ k,
                                               const int* __restrict__ pos) {
  int idx = blockIdx.x * 256 + threadIdx.x;  // 2,097,152 threads
  int i = idx & 31;
  int s = (idx >> 5) & 2047;
  int bh = idx >> 16;
  int b = bh >> 4;
  float p = (float)pos[b * 2048 + s];
  float inv = exp2f(-(float)i * 0.4152410118609203f);
  float ang = p * inv;
  float sn = sinf(ang), cs = cosf(ang);
  size_t base = (((size_t)bh * 2048) + s) * 64 + 2 * i;
  float q1 = bf2f(q[base]), q2 = bf2f(q[base + 1]);
  q[base]     = f2bf(q1 * cs - q2 * sn);
  q[base + 1] = f2bf(q1 * sn + q2 * cs);
  float k1 = bf2f(k[base]), k2 = bf2f(k[base + 1]);
  k[base]     = f2bf(k1 * cs - k2 * sn);
  k[base + 1] = f2bf(k1 * sn + k2 * cs);
}

// ================= 256x256 8-phase GEMM =================
template <int MODE>
DEV void gemm8_body(const unsigned short* __restrict__ A, int lda,
                    const unsigned short* __restrict__ B, int ldb,
                    int bm, int bn, int kbase, int nt,
                    unsigned short* __restrict__ outb, float* __restrict__ outf,
                    const float* __restrict__ resid, const unsigned short* __restrict__ gate,
                    unsigned short* As, unsigned short* Bs) {
  const int tid = threadIdx.x;
  const int lane = tid & 63, wid = tid >> 6;
  const int wr = wid >> 2, wc = wid & 3;
  const int m0 = bm * 256, n0 = bn * 256;

  const int r0 = tid >> 2, r1 = 128 + (tid >> 2), cc = tid & 3;
  const int sc0 = (cc ^ ((r0 >> 1) & 3)) * 8;
  const int sc1 = (cc ^ ((r1 >> 1) & 3)) * 8;
  const size_t arow0 = (size_t)(m0 + r0) * lda, arow1 = (size_t)(m0 + r1) * lda;
  const size_t brow0 = (size_t)(n0 + r0) * ldb, brow1 = (size_t)(n0 + r1) * ldb;
  const int du0 = tid * 8, du1 = (512 + tid) * 8;

  auto stA = [&](int t, int kh) {
    unsigned short* d = As + ((((t & 1) << 1) | kh) * 8192);
    const unsigned short* s = A + kbase + t * 64 + kh * 32;
    gload_lds16(s + arow0 + sc0, d + du0);
    gload_lds16(s + arow1 + sc1, d + du1);
  };
  auto stB = [&](int t, int kh) {
    unsigned short* d = Bs + ((((t & 1) << 1) | kh) * 8192);
    const unsigned short* s = B + kbase + t * 64 + kh * 32;
    gload_lds16(s + brow0 + sc0, d + du0);
    gload_lds16(s + brow1 + sc1, d + du1);
  };

  const int fcol = ((lane >> 4) ^ ((lane >> 1) & 3)) * 8;
  const int frow = lane & 15;
  const int abase = (wr * 128 + frow) * 32 + fcol;
  const int bbase = (wc * 64 + frow) * 32 + fcol;

  f32x4 acc[8][4] = {};
  bf16x8 a[4], b[4];

#define LOADA(buf, ks, mh) { const unsigned short* p_ = As + (((buf) << 1) | (ks)) * 8192 + abase + (mh) * 2048; \
  a[0] = *(const bf16x8*)(p_); a[1] = *(const bf16x8*)(p_ + 512); \
  a[2] = *(const bf16x8*)(p_ + 1024); a[3] = *(const bf16x8*)(p_ + 1536); }
#define LOADB(buf, ks) { const unsigned short* p_ = Bs + (((buf) << 1) | (ks)) * 8192 + bbase; \
  b[0] = *(const bf16x8*)(p_); b[1] = *(const bf16x8*)(p_ + 512); \
  b[2] = *(const bf16x8*)(p_ + 1024); b[3] = *(const bf16x8*)(p_ + 1536); }
#define MFMAQ(mh) { _Pragma("unroll") for (int fi = 0; fi < 4; ++fi) \
  _Pragma("unroll") for (int j = 0; j < 4; ++j) \
    acc[(mh) * 4 + fi][j] = mfma16(a[fi], b[j], acc[(mh) * 4 + fi][j]); }
#define LGK0() { asm volatile("s_waitcnt lgkmcnt(0)" ::: "memory"); __builtin_amdgcn_sched_barrier(0); }

  stA(0, 0); stB(0, 0); stA(0, 1); stB(0, 1);
  stA(1, 0); stB(1, 0);
  asm volatile("s_waitcnt vmcnt(4)" ::: "memory");
  __builtin_amdgcn_s_barrier();

  for (int t = 0; t < nt; ++t) {
    const int buf = t & 1;
    LOADA(buf, 0, 0); LOADB(buf, 0);
    if (t + 1 < nt) stA(t + 1, 1);
    __builtin_amdgcn_s_barrier();
    LGK0();
    __builtin_amdgcn_s_setprio(1); MFMAQ(0); __builtin_amdgcn_s_setprio(0);
    __builtin_amdgcn_s_barrier();
    LOADA(buf, 0, 1);
    if (t + 1 < nt) stB(t + 1, 1);
    __builtin_amdgcn_s_barrier();
    LGK0();
    __builtin_amdgcn_s_setprio(1); MFMAQ(1); __builtin_amdgcn_s_setprio(0);
    __builtin_amdgcn_s_barrier();
    LOADA(buf, 1, 0); LOADB(buf, 1);
    if (t + 2 < nt) stA(t + 2, 0);
    __builtin_amdgcn_s_barrier();
    LGK0();
    __builtin_amdgcn_s_setprio(1); MFMAQ(0); __builtin_amdgcn_s_setprio(0);
    __builtin_amdgcn_s_barrier();
    LOADA(buf, 1, 1);
    if (t + 2 < nt) stB(t + 2, 0);
    __builtin_amdgcn_s_barrier();
    LGK0();
    __builtin_amdgcn_s_setprio(1); MFMAQ(1); __builtin_amdgcn_s_setprio(0);
    if (t + 1 < nt) {
      if (t + 2 < nt) { asm volatile("s_waitcnt vmcnt(4)" ::: "memory"); }
      else            { asm volatile("s_waitcnt vmcnt(0)" ::: "memory"); }
      __builtin_amdgcn_s_barrier();
    }
  }
#undef LOADA
#undef LOADB
#undef MFMAQ
#undef LGK0

#pragma unroll
  for (int i = 0; i < 8; ++i)
#pragma unroll
    for (int j = 0; j < 4; ++j)
#pragma unroll
      for (int r = 0; r < 4; ++r) {
        int m = m0 + wr * 128 + i * 16 + ((lane >> 4) << 2) + r;
        int n = n0 + wc * 64 + j * 16 + (lane & 15);
        float v = acc[i][j][r];
        if (MODE == 0) {
          unsigned short* dst = outb + ((n >= 1024) ? 4194304 : 0);
          int nn = n & 1023;
          int bb = m >> 11, s = m & 2047, hh = nn >> 6, dd = nn & 63;
          dst[(((size_t)bb * 16 + hh) * 2048 + s) * 64 + dd] = f2bf(v);
        } else if (MODE == 1) {
          int hh = m >> 6, dd = m & 63, bb = n >> 11, s = n & 2047;
          outb[(((size_t)bb * 16 + hh) * 64 + dd) * 2048 + s] = f2bf(v);
        } else if (MODE == 2) {
          size_t idx = (size_t)m * 1024 + n;
          outf[idx] = resid[idx] + v;
        } else if (MODE == 3) {
          outb[(size_t)m * 4096 + n] = f2bf(v);
        } else {
          size_t idx = (size_t)m * 4096 + n;
          float g = bf2f(gate[idx]);
          outb[idx] = f2bf(g / (1.0f + __expf(-g)) * v);
        }
      }
}

DEV void swz_map(int bid, int nwg, int MT, int& bm, int& bn) {
  int cpx = nwg >> 3;
  int sw = (bid & 7) * cpx + (bid >> 3);
  bm = sw % MT;
  bn = sw / MT;
}

template <int MODE>
__global__ __launch_bounds__(512, 2) void gemm8_k(const unsigned short* __restrict__ A, int lda,
                                                  const unsigned short* __restrict__ B, int ldb,
                                                  int MT, int nt,
                                                  unsigned short* __restrict__ outb,
                                                  float* __restrict__ outf,
                                                  const float* __restrict__ resid,
                                                  const unsigned short* __restrict__ gate) {
  __shared__ __align__(16) unsigned short lds[65536];
  int bm, bn;
  swz_map(blockIdx.x, gridDim.x, MT, bm, bn);
  gemm8_body<MODE>(A, lda, B, ldb, bm, bn, 0, nt, outb, outf, resid, gate, lds, lds + 32768);
}

__global__ __launch_bounds__(512, 2) void gemm8_qkv(const unsigned short* __restrict__ xn,
                                                    const unsigned short* __restrict__ wqk,
                                                    const unsigned short* __restrict__ wv,
                                                    unsigned short* __restrict__ qk_out,
                                                    unsigned short* __restrict__ vt_out) {
  __shared__ __align__(16) unsigned short lds[65536];
  int bid = blockIdx.x;
  if (bid < 128) {
    int bm, bn;
    swz_map(bid, 128, 16, bm, bn);
    gemm8_body<0>(xn, 1024, wqk, 1024, bm, bn, 0, 16, qk_out, nullptr, nullptr, nullptr, lds, lds + 32768);
  } else {
    bid -= 128;
    int bm, bn;
    swz_map(bid, 64, 4, bm, bn);
    gemm8_body<1>(wv, 1024, xn, 1024, bm, bn, 0, 16, vt_out, nullptr, nullptr, nullptr, lds, lds + 32768);
  }
}

// ---------------- 128x128 2-phase GEMM, fp32 out = resid + acc (N=1024) ----------------
template <int K>
__global__ __launch_bounds__(256) void gemm_res(const unsigned short* __restrict__ A,
                                                const unsigned short* __restrict__ Bw,
                                                float* __restrict__ outf,
                                                const float* __restrict__ resid) {
  __shared__ __align__(16) unsigned short As[128 * 64];
  __shared__ __align__(16) unsigned short Bs[128 * 64];
  const int N = 1024;
  const int tid = threadIdx.x;
  const int wid = tid >> 6, lane = tid & 63;
  const int wr = wid >> 1, wc = wid & 1;
  const int m0 = blockIdx.x * 128, n0 = blockIdx.y * 128;
  const int sw = (lane & 7) * 8;
  f32x4 acc[4][4] = {};

  for (int k0 = 0; k0 < K; k0 += 64) {
    __syncthreads();
#pragma unroll
    for (int it = 0; it < 4; ++it) {
      int c = wid * 4 + it;
      int row = c * 8 + (lane >> 3);
      int col = ((lane & 7) ^ (row & 7)) * 8;
      gload_lds16(A + (size_t)(m0 + row) * K + k0 + col, As + c * 512);
      gload_lds16(Bw + (size_t)(n0 + row) * K + k0 + col, Bs + c * 512);
    }
    asm volatile("s_waitcnt vmcnt(0)" ::: "memory");
    __syncthreads();
#pragma unroll
    for (int kk = 0; kk < 2; ++kk) {
      const int kof = (kk * 32 + (lane >> 4) * 8) ^ sw;
      bf16x8 af[4], bfr[4];
#pragma unroll
      for (int i = 0; i < 4; ++i) {
        af[i]  = *(const bf16x8*)(As + (wr * 64 + i * 16 + (lane & 15)) * 64 + kof);
        bfr[i] = *(const bf16x8*)(Bs + (wc * 64 + i * 16 + (lane & 15)) * 64 + kof);
      }
#pragma unroll
      for (int i = 0; i < 4; ++i)
#pragma unroll
        for (int j = 0; j < 4; ++j) acc[i][j] = mfma16(af[i], bfr[j], acc[i][j]);
    }
  }
  const int rb = m0 + wr * 64 + ((lane >> 4) * 4);
  const int cb = n0 + wc * 64 + (lane & 15);
#pragma unroll
  for (int i = 0; i < 4; ++i)
#pragma unroll
    for (int r = 0; r < 4; ++r) {
      int m = rb + i * 16 + r;
#pragma unroll
      for (int j = 0; j < 4; ++j) {
        size_t idx = (size_t)m * N + cb + j * 16;
        outf[idx] = resid[idx] + acc[i][j][r];
      }
    }
}

// ---------------- Flash attention: round-4 skeleton + swapped-QK 16x16 ----------------
// q,k: [BH][S][64] bf16 (RoPE'd); vt: V^T [BH][64][S]; ctx: [B][S][1024]
// 1024 blocks x 256 thr (4 waves, 16 q-rows each), dbuf K/V, counted vmcnt.
// S = mfma16(K, Q): lane's S column = its own q-row -> scalar m/l, 2 shfl/iter,
// P stored with ds_write_b64 (consecutive keys per lane).
__global__ __launch_bounds__(256) void attn_k(const unsigned short* __restrict__ q,
                                              const unsigned short* __restrict__ k,
                                              const unsigned short* __restrict__ vt,
                                              unsigned short* __restrict__ ctx) {
  __shared__ __align__(16) unsigned short Ks[2][4096];
  __shared__ __align__(16) unsigned short Vs[2][4096];
  __shared__ __align__(16) unsigned short Ps[4][16 * 72];
  const int bid = blockIdx.x;                       // 1024 blocks
  const int bh = (bid & 7) * 4 + ((bid >> 3) & 3);  // XCD-pinned: 4 heads/XCD
  const int qt = 31 - (bid >> 5);                   // longest first
  const int tid = threadIdx.x, wid = tid >> 6, lane = tid & 63;
  const size_t bhS = (size_t)bh * 2048;
  const size_t bhD = (size_t)bh * 64 * 2048;
  const int b = bh >> 4, hh = bh & 15;
  const int sw = (lane & 7) * 8;
  const int h4 = lane >> 4, l15 = lane & 15;
  const float SC2 = 0.18033688011112042f;  // 0.125 * log2(e)

  const int c0 = wid * 2, c1 = wid * 2 + 1;
  const int row0 = c0 * 8 + (lane >> 3), row1 = c1 * 8 + (lane >> 3);
  const int col0 = ((lane & 7) ^ (row0 & 7)) * 8;
  const int col1 = ((lane & 7) ^ (row1 & 7)) * 8;

  auto stage = [&](int kt, int buf) {
    gload_lds16(k + (bhS + kt * 64 + row0) * 64 + col0, &Ks[buf][c0 * 512]);
    gload_lds16(k + (bhS + kt * 64 + row1) * 64 + col1, &Ks[buf][c1 * 512]);
    gload_lds16(vt + bhD + (size_t)row0 * 2048 + kt * 64 + col0, &Vs[buf][c0 * 512]);
    gload_lds16(vt + bhD + (size_t)row1 * 2048 + kt * 64 + col1, &Vs[buf][c1 * 512]);
  };

  const int q0 = qt * 64;
  bf16x8 qf[2];
  {
    const unsigned short* qp = q + (bhS + q0 + wid * 16 + l15) * 64 + h4 * 8;
    qf[0] = *(const bf16x8*)qp;
    qf[1] = *(const bf16x8*)(qp + 32);
#pragma unroll
    for (int jj = 0; jj < 8; ++jj) {
      qf[0][jj] = (__bf16)((float)qf[0][jj] * SC2);
      qf[1][jj] = (__bf16)((float)qf[1][jj] * SC2);
    }
  }
  float mrow = -1e30f, lrow = 0.0f;
  f32x4 o[4] = {};
  const int qg = q0 + wid * 16 + l15;          // lane's own q (S column)
  const int rowb = q0 + wid * 16 + (h4 << 2);  // output q rows

  stage(0, 0);
  if (qt > 0) { stage(1, 1); asm volatile("s_waitcnt vmcnt(4)" ::: "memory"); }
  else        {              asm volatile("s_waitcnt vmcnt(0)" ::: "memory"); }
  __builtin_amdgcn_s_barrier();

  for (int kt = 0; kt <= qt; ++kt) {
    const int cur = kt & 1;
    // ---- S = K . Q^T (swapped): lane holds S[key=(h4*4+r)+16nt][q=own]
    float s[16];
#pragma unroll
    for (int nt = 0; nt < 4; ++nt) {
      f32x4 z = {};
#pragma unroll
      for (int ks = 0; ks < 2; ++ks) {
        int kof = (ks * 32 + h4 * 8) ^ sw;
        bf16x8 kf = *(const bf16x8*)(&Ks[cur][(nt * 16 + l15) * 64 + kof]);
        z = mfma16(kf, qf[ks], z);
      }
      s[nt * 4 + 0] = z[0]; s[nt * 4 + 1] = z[1];
      s[nt * 4 + 2] = z[2]; s[nt * 4 + 3] = z[3];
    }
    // ---- causal mask (diagonal tile only)
    if (kt == qt) {
#pragma unroll
      for (int nt = 0; nt < 4; ++nt)
#pragma unroll
        for (int r = 0; r < 4; ++r) {
          int key = q0 + nt * 16 + (h4 << 2) + r;
          if (key > qg) s[nt * 4 + r] = -3e38f;
        }
    }
    // ---- row max: 15 local fmax + 2 shfl
    float pmax = s[0];
#pragma unroll
    for (int i = 1; i < 16; ++i) pmax = fmaxf(pmax, s[i]);
    pmax = fmaxf(pmax, __shfl_xor(pmax, 16));
    pmax = fmaxf(pmax, __shfl_xor(pmax, 32));
    // ---- defer-max rescale (rare)
    if (!__all(pmax <= mrow + 11.5f)) {
      float mnew = fmaxf(mrow, pmax);
      float dl = mrow - mnew;
      mrow = mnew;
      lrow *= fexp2(dl);
#pragma unroll
      for (int r = 0; r < 4; ++r) {
        float ar = fexp2(__shfl(dl, (h4 << 2) + r, 16));
#pragma unroll
        for (int d = 0; d < 4; ++d) o[d][r] *= ar;
      }
    }
    // ---- P = exp2(S - m), lane-local sum (scalar lrow)
    float sum = 0.0f;
#pragma unroll
    for (int i = 0; i < 16; ++i) { s[i] = fexp2(s[i] - mrow); sum += s[i]; }
    lrow += sum;
    // ---- P -> LDS [q][key] (pad 72), vectorized b64 stores of 4 consecutive keys
    {
      unsigned short* pr = &Ps[wid][l15 * 72 + (h4 << 2)];
#pragma unroll
      for (int nt = 0; nt < 4; ++nt) {
        uint2 w;
        w.x = pkbf(s[4 * nt], s[4 * nt + 1]);
        w.y = pkbf(s[4 * nt + 2], s[4 * nt + 3]);
        *(uint2*)(pr + nt * 16) = w;
      }
    }
    // ---- PV: A = P[q][key] (b128), B = V[d][key]
#pragma unroll
    for (int ks = 0; ks < 2; ++ks) {
      bf16x8 pf = *(const bf16x8*)(&Ps[wid][l15 * 72 + ks * 32 + (h4 << 3)]);
      int kof = (ks * 32 + h4 * 8) ^ sw;
#pragma unroll
      for (int d = 0; d < 4; ++d) {
        bf16x8 vf = *(const bf16x8*)(&Vs[cur][(d * 16 + l15) * 64 + kof]);
        o[d] = mfma16(pf, vf, o[d]);
      }
    }
    __builtin_amdgcn_s_barrier();
    if (kt + 2 <= qt) {
      stage(kt + 2, cur);
      asm volatile("s_waitcnt vmcnt(4)" ::: "memory");
    } else if (kt + 1 <= qt) {
      asm volatile("s_waitcnt vmcnt(0)" ::: "memory");
    }
    __builtin_amdgcn_s_barrier();
  }
  // ---- final l reduce + normalize
  lrow += __shfl_xor(lrow, 16);
  lrow += __shfl_xor(lrow, 32);
  float inv = 1.0f / lrow;
#pragma unroll
  for (int r = 0; r < 4; ++r) {
    float invr = __shfl(inv, (h4 << 2) + r, 16);
#pragma unroll
    for (int d = 0; d < 4; ++d)
      ctx[((size_t)b * 2048 + (rowb + r)) * 1024 + hh * 64 + d * 16 + l15] = f2bf(o[d][r] * invr);
  }
}

extern "C" void kernel_launch(void* const* d_in, const int* in_sizes, int n_in,
                              void* d_out, int out_size, void* d_ws, size_t ws_size,
                              hipStream_t stream) {
  (void)in_sizes; (void)n_in; (void)out_size; (void)ws_size;
  const float* in_f = (const float*)d_in[0];
  const int* pos    = (const int*)d_in[1];
  const float* q_w  = (const float*)d_in[2];
  const float* k_w  = (const float*)d_in[3];
  const float* v_w  = (const float*)d_in[4];
  const float* o_w  = (const float*)d_in[5];
  const float* ln1  = (const float*)d_in[6];
  const float* ln2  = (const float*)d_in[7];
  const float* w1   = (const float*)d_in[8];
  const float* w2   = (const float*)d_in[9];
  const float* w3   = (const float*)d_in[10];
  float* out = (float*)d_out;

  unsigned short* ws = (unsigned short*)d_ws;
  unsigned short* wb   = ws;
  unsigned short* wqkb = wb;
  unsigned short* wvb  = wb + 2097152;
  unsigned short* wob  = wb + 3145728;
  unsigned short* w1b  = wb + 4194304;
  unsigned short* w2b  = wb + 8388608;
  unsigned short* w3b  = wb + 12582912;
  unsigned short* xn   = ws + 16777216;
  unsigned short* qb   = ws + 20971520;
  unsigned short* kb   = ws + 25165824;   // must be qb + 4194304
  unsigned short* vb   = ws + 29360128;   // V^T [bh][64][2048]
  unsigned short* cx   = ws + 33554432;
  unsigned short* gb   = ws + 37748736;
  unsigned short* hb   = ws + 54525952;

  CvtArgs ca;
  ca.src[0] = q_w; ca.src[1] = k_w; ca.src[2] = v_w; ca.src[3] = o_w;
  ca.src[4] = w1;  ca.src[5] = w2;  ca.src[6] = w3;
  ca.cum[0] = 0;        ca.cum[1] = 1048576;  ca.cum[2] = 2097152;  ca.cum[3] = 3145728;
  ca.cum[4] = 4194304;  ca.cum[5] = 8388608;  ca.cum[6] = 12582912; ca.cum[7] = 16777216;
  cvt_all<<<16384, 256, 0, stream>>>(ca, wb);

  rmsnorm_k<<<4096, 256, 0, stream>>>(in_f, ln1, xn);

  gemm8_qkv<<<192, 512, 0, stream>>>(xn, wqkb, wvb, qb, vb);

  rope2_k<<<8192, 256, 0, stream>>>(qb, kb, pos);

  attn_k<<<1024, 256, 0, stream>>>(qb, kb, vb, cx);

  gemm_res<1024><<<dim3(32, 8), 256, 0, stream>>>(cx, wob, out, in_f);

  rmsnorm_k<<<4096, 256, 0, stream>>>(out, ln2, xn);

  gemm8_k<3><<<256, 512, 0, stream>>>(xn, 1024, w1b, 1024, 16, 16, gb, nullptr, nullptr, nullptr);
  gemm8_k<4><<<256, 512, 0, stream>>>(xn, 1024, w3b, 1024, 16, 16, hb, nullptr, nullptr, gb);

  gemm_res<4096><<<dim3(32, 8), 256, 0, stream>>>(hb, w2b, out, out);
}

// Round 9
// 283.610 us; speedup vs baseline: 1.1072x; 1.0369x over previous
//
#include <hip/hip_runtime.h>
#include <hip/hip_bf16.h>

typedef __attribute__((ext_vector_type(8))) __bf16 bf16x8;
typedef __attribute__((ext_vector_type(4))) float f32x4;

#define DEV static __device__ __forceinline__

DEV unsigned short f2bf(float f) {
  __bf16 h = (__bf16)f;
  union { __bf16 h; unsigned short u; } v; v.h = h;
  return v.u;
}
DEV float bf2f(unsigned short h) {
  union { unsigned int u; float f; } v; v.u = ((unsigned int)h) << 16;
  return v.f;
}
DEV unsigned pkbf(float lo, float hi) {
  union { __bf16 h[2]; unsigned u; } v;
  v.h[0] = (__bf16)lo; v.h[1] = (__bf16)hi;
  return v.u;
}
DEV f32x4 mfma16(bf16x8 a, bf16x8 b, f32x4 c) {
  return __builtin_amdgcn_mfma_f32_16x16x32_bf16(a, b, c, 0, 0, 0);
}
DEV void gload_lds16(const void* g, void* l) {
  __builtin_amdgcn_global_load_lds((__attribute__((address_space(1))) void*)g,
                                   (__attribute__((address_space(3))) void*)l,
                                   16, 0, 0);
}
DEV float fexp2(float x) { return exp2f(x); }

// ---------------- fused f32 -> bf16 convert of all 7 weights ----------------
struct CvtArgs { const float* src[7]; int cum[8]; };
__global__ __launch_bounds__(256) void cvt_all(CvtArgs a, unsigned short* __restrict__ dst) {
  int i = (blockIdx.x * 256 + threadIdx.x) * 4;
  if (i >= a.cum[7]) return;
  int w = 0;
#pragma unroll 7
  for (int t = 0; t < 7; ++t) if (i >= a.cum[t + 1]) w = t + 1;
  float4 v = *(const float4*)(a.src[w] + (i - a.cum[w]));
  dst[i + 0] = f2bf(v.x);
  dst[i + 1] = f2bf(v.y);
  dst[i + 2] = f2bf(v.z);
  dst[i + 3] = f2bf(v.w);
}

// ---------------- RMSNorm: fp32 in -> bf16 out (D=1024) ----------------
__global__ __launch_bounds__(256) void rmsnorm_k(const float* __restrict__ x,
                                                 const float* __restrict__ w,
                                                 unsigned short* __restrict__ out) {
  int row = blockIdx.x;
  int tid = threadIdx.x;
  const float* xr = x + (size_t)row * 1024;
  float4 v = *(const float4*)(xr + tid * 4);
  float ss = v.x * v.x + v.y * v.y + v.z * v.z + v.w * v.w;
#pragma unroll
  for (int m = 32; m >= 1; m >>= 1) ss += __shfl_xor(ss, m);
  __shared__ float red[4];
  int wid = tid >> 6;
  if ((tid & 63) == 0) red[wid] = ss;
  __syncthreads();
  float tot = red[0] + red[1] + red[2] + red[3];
  float rs = rsqrtf(tot * (1.0f / 1024.0f) + 1e-5f);
  float4 wv = *(const float4*)(w + tid * 4);
  unsigned short* o = out + (size_t)row * 1024 + tid * 4;
  o[0] = f2bf(v.x * rs * wv.x);
  o[1] = f2bf(v.y * rs * wv.y);
  o[2] = f2bf(v.z * rs * wv.z);
  o[3] = f2bf(v.w * rs * wv.w);
}

// ---------------- RoPE in-place: one thread rotates q AND k ----------------
__global__ __launch_bounds__(256) void rope2_k(unsigned short* __restrict__ q,
                                               unsigned short* __restrict__ k,
                                               const int* __restrict__ pos) {
  int idx = blockIdx.x * 256 + threadIdx.x;  // 2,097,152 threads
  int i = idx & 31;
  int s = (idx >> 5) & 2047;
  int bh = idx >> 16;
  int b = bh >> 4;
  float p = (float)pos[b * 2048 + s];
  float inv = exp2f(-(float)i * 0.4152410118609203f);
  float ang = p * inv;
  float sn = sinf(ang), cs = cosf(ang);
  size_t base = (((size_t)bh * 2048) + s) * 64 + 2 * i;
  float q1 = bf2f(q[base]), q2 = bf2f(q[base + 1]);
  q[base]     = f2bf(q1 * cs - q2 * sn);
  q[base + 1] = f2bf(q1 * sn + q2 * cs);
  float k1 = bf2f(k[base]), k2 = bf2f(k[base + 1]);
  k[base]     = f2bf(k1 * cs - k2 * sn);
  k[base + 1] = f2bf(k1 * sn + k2 * cs);
}

// ================= 256x256 8-phase GEMM =================
template <int MODE>
DEV void gemm8_body(const unsigned short* __restrict__ A, int lda,
                    const unsigned short* __restrict__ B, int ldb,
                    int bm, int bn, int kbase, int nt,
                    unsigned short* __restrict__ outb, float* __restrict__ outf,
                    const float* __restrict__ resid, const unsigned short* __restrict__ gate,
                    unsigned short* As, unsigned short* Bs) {
  const int tid = threadIdx.x;
  const int lane = tid & 63, wid = tid >> 6;
  const int wr = wid >> 2, wc = wid & 3;
  const int m0 = bm * 256, n0 = bn * 256;

  const int r0 = tid >> 2, r1 = 128 + (tid >> 2), cc = tid & 3;
  const int sc0 = (cc ^ ((r0 >> 1) & 3)) * 8;
  const int sc1 = (cc ^ ((r1 >> 1) & 3)) * 8;
  const size_t arow0 = (size_t)(m0 + r0) * lda, arow1 = (size_t)(m0 + r1) * lda;
  const size_t brow0 = (size_t)(n0 + r0) * ldb, brow1 = (size_t)(n0 + r1) * ldb;
  const int du0 = tid * 8, du1 = (512 + tid) * 8;

  auto stA = [&](int t, int kh) {
    unsigned short* d = As + ((((t & 1) << 1) | kh) * 8192);
    const unsigned short* s = A + kbase + t * 64 + kh * 32;
    gload_lds16(s + arow0 + sc0, d + du0);
    gload_lds16(s + arow1 + sc1, d + du1);
  };
  auto stB = [&](int t, int kh) {
    unsigned short* d = Bs + ((((t & 1) << 1) | kh) * 8192);
    const unsigned short* s = B + kbase + t * 64 + kh * 32;
    gload_lds16(s + brow0 + sc0, d + du0);
    gload_lds16(s + brow1 + sc1, d + du1);
  };

  const int fcol = ((lane >> 4) ^ ((lane >> 1) & 3)) * 8;
  const int frow = lane & 15;
  const int abase = (wr * 128 + frow) * 32 + fcol;
  const int bbase = (wc * 64 + frow) * 32 + fcol;

  f32x4 acc[8][4] = {};
  bf16x8 a[4], b[4];

#define LOADA(buf, ks, mh) { const unsigned short* p_ = As + (((buf) << 1) | (ks)) * 8192 + abase + (mh) * 2048; \
  a[0] = *(const bf16x8*)(p_); a[1] = *(const bf16x8*)(p_ + 512); \
  a[2] = *(const bf16x8*)(p_ + 1024); a[3] = *(const bf16x8*)(p_ + 1536); }
#define LOADB(buf, ks) { const unsigned short* p_ = Bs + (((buf) << 1) | (ks)) * 8192 + bbase; \
  b[0] = *(const bf16x8*)(p_); b[1] = *(const bf16x8*)(p_ + 512); \
  b[2] = *(const bf16x8*)(p_ + 1024); b[3] = *(const bf16x8*)(p_ + 1536); }
#define MFMAQ(mh) { _Pragma("unroll") for (int fi = 0; fi < 4; ++fi) \
  _Pragma("unroll") for (int j = 0; j < 4; ++j) \
    acc[(mh) * 4 + fi][j] = mfma16(a[fi], b[j], acc[(mh) * 4 + fi][j]); }
#define LGK0() { asm volatile("s_waitcnt lgkmcnt(0)" ::: "memory"); __builtin_amdgcn_sched_barrier(0); }

  stA(0, 0); stB(0, 0); stA(0, 1); stB(0, 1);
  stA(1, 0); stB(1, 0);
  asm volatile("s_waitcnt vmcnt(4)" ::: "memory");
  __builtin_amdgcn_s_barrier();

  for (int t = 0; t < nt; ++t) {
    const int buf = t & 1;
    LOADA(buf, 0, 0); LOADB(buf, 0);
    if (t + 1 < nt) stA(t + 1, 1);
    __builtin_amdgcn_s_barrier();
    LGK0();
    __builtin_amdgcn_s_setprio(1); MFMAQ(0); __builtin_amdgcn_s_setprio(0);
    __builtin_amdgcn_s_barrier();
    LOADA(buf, 0, 1);
    if (t + 1 < nt) stB(t + 1, 1);
    __builtin_amdgcn_s_barrier();
    LGK0();
    __builtin_amdgcn_s_setprio(1); MFMAQ(1); __builtin_amdgcn_s_setprio(0);
    __builtin_amdgcn_s_barrier();
    LOADA(buf, 1, 0); LOADB(buf, 1);
    if (t + 2 < nt) stA(t + 2, 0);
    __builtin_amdgcn_s_barrier();
    LGK0();
    __builtin_amdgcn_s_setprio(1); MFMAQ(0); __builtin_amdgcn_s_setprio(0);
    __builtin_amdgcn_s_barrier();
    LOADA(buf, 1, 1);
    if (t + 2 < nt) stB(t + 2, 0);
    __builtin_amdgcn_s_barrier();
    LGK0();
    __builtin_amdgcn_s_setprio(1); MFMAQ(1); __builtin_amdgcn_s_setprio(0);
    if (t + 1 < nt) {
      if (t + 2 < nt) { asm volatile("s_waitcnt vmcnt(4)" ::: "memory"); }
      else            { asm volatile("s_waitcnt vmcnt(0)" ::: "memory"); }
      __builtin_amdgcn_s_barrier();
    }
  }
#undef LOADA
#undef LOADB
#undef MFMAQ
#undef LGK0

#pragma unroll
  for (int i = 0; i < 8; ++i)
#pragma unroll
    for (int j = 0; j < 4; ++j)
#pragma unroll
      for (int r = 0; r < 4; ++r) {
        int m = m0 + wr * 128 + i * 16 + ((lane >> 4) << 2) + r;
        int n = n0 + wc * 64 + j * 16 + (lane & 15);
        float v = acc[i][j][r];
        if (MODE == 0) {
          unsigned short* dst = outb + ((n >= 1024) ? 4194304 : 0);
          int nn = n & 1023;
          int bb = m >> 11, s = m & 2047, hh = nn >> 6, dd = nn & 63;
          dst[(((size_t)bb * 16 + hh) * 2048 + s) * 64 + dd] = f2bf(v);
        } else if (MODE == 1) {
          int hh = m >> 6, dd = m & 63, bb = n >> 11, s = n & 2047;
          outb[(((size_t)bb * 16 + hh) * 64 + dd) * 2048 + s] = f2bf(v);
        } else if (MODE == 2) {
          size_t idx = (size_t)m * 1024 + n;
          outf[idx] = resid[idx] + v;
        } else if (MODE == 3) {
          outb[(size_t)m * 4096 + n] = f2bf(v);
        } else if (MODE == 4) {
          size_t idx = (size_t)m * 4096 + n;
          float g = bf2f(gate[idx]);
          outb[idx] = f2bf(g / (1.0f + __expf(-g)) * v);
        } else {
          outf[(size_t)m * 1024 + n] = v;
        }
      }
}

DEV void swz_map(int bid, int nwg, int MT, int& bm, int& bn) {
  int cpx = nwg >> 3;
  int sw = (bid & 7) * cpx + (bid >> 3);
  bm = sw % MT;
  bn = sw / MT;
}

template <int MODE>
__global__ __launch_bounds__(512, 2) void gemm8_k(const unsigned short* __restrict__ A, int lda,
                                                  const unsigned short* __restrict__ B, int ldb,
                                                  int MT, int kz, int nt,
                                                  unsigned short* __restrict__ outb,
                                                  float* __restrict__ outf,
                                                  const float* __restrict__ resid,
                                                  const unsigned short* __restrict__ gate) {
  __shared__ __align__(16) unsigned short lds[65536];
  int bm, bn;
  swz_map(blockIdx.x, gridDim.x, MT, bm, bn);
  int kb = kz * blockIdx.y;
  float* of = outf;
  if (MODE == 5) of += (size_t)blockIdx.y * 4194304;
  gemm8_body<MODE>(A, lda, B, ldb, bm, bn, kb, nt, outb, of, resid, gate, lds, lds + 32768);
}

__global__ __launch_bounds__(512, 2) void gemm8_qkv(const unsigned short* __restrict__ xn,
                                                    const unsigned short* __restrict__ wqk,
                                                    const unsigned short* __restrict__ wv,
                                                    unsigned short* __restrict__ qk_out,
                                                    unsigned short* __restrict__ vt_out) {
  __shared__ __align__(16) unsigned short lds[65536];
  int bid = blockIdx.x;
  if (bid < 128) {
    int bm, bn;
    swz_map(bid, 128, 16, bm, bn);
    gemm8_body<0>(xn, 1024, wqk, 1024, bm, bn, 0, 16, qk_out, nullptr, nullptr, nullptr, lds, lds + 32768);
  } else {
    bid -= 128;
    int bm, bn;
    swz_map(bid, 64, 4, bm, bn);
    gemm8_body<1>(wv, 1024, xn, 1024, bm, bn, 0, 16, vt_out, nullptr, nullptr, nullptr, lds, lds + 32768);
  }
}

// ---------------- 128x128 2-phase GEMM, fp32 out = resid + acc (N=1024) ----------------
template <int K>
__global__ __launch_bounds__(256) void gemm_res(const unsigned short* __restrict__ A,
                                                const unsigned short* __restrict__ Bw,
                                                float* __restrict__ outf,
                                                const float* __restrict__ resid) {
  __shared__ __align__(16) unsigned short As[128 * 64];
  __shared__ __align__(16) unsigned short Bs[128 * 64];
  const int N = 1024;
  const int tid = threadIdx.x;
  const int wid = tid >> 6, lane = tid & 63;
  const int wr = wid >> 1, wc = wid & 1;
  const int m0 = blockIdx.x * 128, n0 = blockIdx.y * 128;
  const int sw = (lane & 7) * 8;
  f32x4 acc[4][4] = {};

  for (int k0 = 0; k0 < K; k0 += 64) {
    __syncthreads();
#pragma unroll
    for (int it = 0; it < 4; ++it) {
      int c = wid * 4 + it;
      int row = c * 8 + (lane >> 3);
      int col = ((lane & 7) ^ (row & 7)) * 8;
      gload_lds16(A + (size_t)(m0 + row) * K + k0 + col, As + c * 512);
      gload_lds16(Bw + (size_t)(n0 + row) * K + k0 + col, Bs + c * 512);
    }
    asm volatile("s_waitcnt vmcnt(0)" ::: "memory");
    __syncthreads();
#pragma unroll
    for (int kk = 0; kk < 2; ++kk) {
      const int kof = (kk * 32 + (lane >> 4) * 8) ^ sw;
      bf16x8 af[4], bfr[4];
#pragma unroll
      for (int i = 0; i < 4; ++i) {
        af[i]  = *(const bf16x8*)(As + (wr * 64 + i * 16 + (lane & 15)) * 64 + kof);
        bfr[i] = *(const bf16x8*)(Bs + (wc * 64 + i * 16 + (lane & 15)) * 64 + kof);
      }
#pragma unroll
      for (int i = 0; i < 4; ++i)
#pragma unroll
        for (int j = 0; j < 4; ++j) acc[i][j] = mfma16(af[i], bfr[j], acc[i][j]);
    }
  }
  const int rb = m0 + wr * 64 + ((lane >> 4) * 4);
  const int cb = n0 + wc * 64 + (lane & 15);
#pragma unroll
  for (int i = 0; i < 4; ++i)
#pragma unroll
    for (int r = 0; r < 4; ++r) {
      int m = rb + i * 16 + r;
#pragma unroll
      for (int j = 0; j < 4; ++j) {
        size_t idx = (size_t)m * N + cb + j * 16;
        outf[idx] = resid[idx] + acc[i][j][r];
      }
    }
}

// ---------------- w2 split-K reduce ----------------
__global__ __launch_bounds__(256) void reduce_k(float* __restrict__ out,
                                                const float* __restrict__ part) {
  int i = (blockIdx.x * 256 + threadIdx.x) * 4;
  float4 o = *(const float4*)(out + i);
  float4 p0 = *(const float4*)(part + i);
  float4 p1 = *(const float4*)(part + 4194304 + i);
  float4 p2 = *(const float4*)(part + 8388608 + i);
  float4 p3 = *(const float4*)(part + 12582912 + i);
  o.x += p0.x + p1.x + p2.x + p3.x;
  o.y += p0.y + p1.y + p2.y + p3.y;
  o.z += p0.z + p1.z + p2.z + p3.z;
  o.w += p0.w + p1.w + p2.w + p3.w;
  *(float4*)(out + i) = o;
}

// ---------------- Flash attention: swapped-QK 16x16, dbuf, in-reg softmax ----------------
__global__ __launch_bounds__(256) void attn_k(const unsigned short* __restrict__ q,
                                              const unsigned short* __restrict__ k,
                                              const unsigned short* __restrict__ vt,
                                              unsigned short* __restrict__ ctx) {
  __shared__ __align__(16) unsigned short Ks[2][4096];
  __shared__ __align__(16) unsigned short Vs[2][4096];
  __shared__ __align__(16) unsigned short Ps[4][16 * 72];
  const int bid = blockIdx.x;                       // 1024 blocks
  const int bh = (bid & 7) * 4 + ((bid >> 3) & 3);  // XCD-pinned: 4 heads/XCD
  const int qt = 31 - (bid >> 5);                   // longest first
  const int tid = threadIdx.x, wid = tid >> 6, lane = tid & 63;
  const size_t bhS = (size_t)bh * 2048;
  const size_t bhD = (size_t)bh * 64 * 2048;
  const int b = bh >> 4, hh = bh & 15;
  const int sw = (lane & 7) * 8;
  const int h4 = lane >> 4, l15 = lane & 15;
  const float SC2 = 0.18033688011112042f;  // 0.125 * log2(e)

  const int c0 = wid * 2, c1 = wid * 2 + 1;
  const int row0 = c0 * 8 + (lane >> 3), row1 = c1 * 8 + (lane >> 3);
  const int col0 = ((lane & 7) ^ (row0 & 7)) * 8;
  const int col1 = ((lane & 7) ^ (row1 & 7)) * 8;

  auto stage = [&](int kt, int buf) {
    gload_lds16(k + (bhS + kt * 64 + row0) * 64 + col0, &Ks[buf][c0 * 512]);
    gload_lds16(k + (bhS + kt * 64 + row1) * 64 + col1, &Ks[buf][c1 * 512]);
    gload_lds16(vt + bhD + (size_t)row0 * 2048 + kt * 64 + col0, &Vs[buf][c0 * 512]);
    gload_lds16(vt + bhD + (size_t)row1 * 2048 + kt * 64 + col1, &Vs[buf][c1 * 512]);
  };

  const int q0 = qt * 64;
  bf16x8 qf[2];
  {
    const unsigned short* qp = q + (bhS + q0 + wid * 16 + l15) * 64 + h4 * 8;
    qf[0] = *(const bf16x8*)qp;
    qf[1] = *(const bf16x8*)(qp + 32);
#pragma unroll
    for (int jj = 0; jj < 8; ++jj) {
      qf[0][jj] = (__bf16)((float)qf[0][jj] * SC2);
      qf[1][jj] = (__bf16)((float)qf[1][jj] * SC2);
    }
  }
  float mrow = -1e30f, lrow = 0.0f;
  f32x4 o[4] = {};
  const int qg = q0 + wid * 16 + l15;          // lane's own q (S column)
  const int rowb = q0 + wid * 16 + (h4 << 2);  // output q rows

  stage(0, 0);
  if (qt > 0) { stage(1, 1); asm volatile("s_waitcnt vmcnt(4)" ::: "memory"); }
  else        {              asm volatile("s_waitcnt vmcnt(0)" ::: "memory"); }
  __builtin_amdgcn_s_barrier();

  for (int kt = 0; kt <= qt; ++kt) {
    const int cur = kt & 1;
    float s[16];
#pragma unroll
    for (int nt = 0; nt < 4; ++nt) {
      f32x4 z = {};
#pragma unroll
      for (int ks = 0; ks < 2; ++ks) {
        int kof = (ks * 32 + h4 * 8) ^ sw;
        bf16x8 kf = *(const bf16x8*)(&Ks[cur][(nt * 16 + l15) * 64 + kof]);
        z = mfma16(kf, qf[ks], z);
      }
      s[nt * 4 + 0] = z[0]; s[nt * 4 + 1] = z[1];
      s[nt * 4 + 2] = z[2]; s[nt * 4 + 3] = z[3];
    }
    if (kt == qt) {
#pragma unroll
      for (int nt = 0; nt < 4; ++nt)
#pragma unroll
        for (int r = 0; r < 4; ++r) {
          int key = q0 + nt * 16 + (h4 << 2) + r;
          if (key > qg) s[nt * 4 + r] = -3e38f;
        }
    }
    float pmax = s[0];
#pragma unroll
    for (int i = 1; i < 16; ++i) pmax = fmaxf(pmax, s[i]);
    pmax = fmaxf(pmax, __shfl_xor(pmax, 16));
    pmax = fmaxf(pmax, __shfl_xor(pmax, 32));
    if (!__all(pmax <= mrow + 11.5f)) {
      float mnew = fmaxf(mrow, pmax);
      float dl = mrow - mnew;
      mrow = mnew;
      lrow *= fexp2(dl);
#pragma unroll
      for (int r = 0; r < 4; ++r) {
        float ar = fexp2(__shfl(dl, (h4 << 2) + r, 16));
#pragma unroll
        for (int d = 0; d < 4; ++d) o[d][r] *= ar;
      }
    }
    float sum = 0.0f;
#pragma unroll
    for (int i = 0; i < 16; ++i) { s[i] = fexp2(s[i] - mrow); sum += s[i]; }
    lrow += sum;
    {
      unsigned short* pr = &Ps[wid][l15 * 72 + (h4 << 2)];
#pragma unroll
      for (int nt = 0; nt < 4; ++nt) {
        uint2 w;
        w.x = pkbf(s[4 * nt], s[4 * nt + 1]);
        w.y = pkbf(s[4 * nt + 2], s[4 * nt + 3]);
        *(uint2*)(pr + nt * 16) = w;
      }
    }
#pragma unroll
    for (int ks = 0; ks < 2; ++ks) {
      bf16x8 pf = *(const bf16x8*)(&Ps[wid][l15 * 72 + ks * 32 + (h4 << 3)]);
      int kof = (ks * 32 + h4 * 8) ^ sw;
#pragma unroll
      for (int d = 0; d < 4; ++d) {
        bf16x8 vf = *(const bf16x8*)(&Vs[cur][(d * 16 + l15) * 64 + kof]);
        o[d] = mfma16(pf, vf, o[d]);
      }
    }
    __builtin_amdgcn_s_barrier();
    if (kt + 2 <= qt) {
      stage(kt + 2, cur);
      asm volatile("s_waitcnt vmcnt(4)" ::: "memory");
    } else if (kt + 1 <= qt) {
      asm volatile("s_waitcnt vmcnt(0)" ::: "memory");
    }
    __builtin_amdgcn_s_barrier();
  }
  lrow += __shfl_xor(lrow, 16);
  lrow += __shfl_xor(lrow, 32);
  float inv = 1.0f / lrow;
#pragma unroll
  for (int r = 0; r < 4; ++r) {
    float invr = __shfl(inv, (h4 << 2) + r, 16);
#pragma unroll
    for (int d = 0; d < 4; ++d)
      ctx[((size_t)b * 2048 + (rowb + r)) * 1024 + hh * 64 + d * 16 + l15] = f2bf(o[d][r] * invr);
  }
}

extern "C" void kernel_launch(void* const* d_in, const int* in_sizes, int n_in,
                              void* d_out, int out_size, void* d_ws, size_t ws_size,
                              hipStream_t stream) {
  (void)in_sizes; (void)n_in; (void)out_size; (void)ws_size;
  const float* in_f = (const float*)d_in[0];
  const int* pos    = (const int*)d_in[1];
  const float* q_w  = (const float*)d_in[2];
  const float* k_w  = (const float*)d_in[3];
  const float* v_w  = (const float*)d_in[4];
  const float* o_w  = (const float*)d_in[5];
  const float* ln1  = (const float*)d_in[6];
  const float* ln2  = (const float*)d_in[7];
  const float* w1   = (const float*)d_in[8];
  const float* w2   = (const float*)d_in[9];
  const float* w3   = (const float*)d_in[10];
  float* out = (float*)d_out;

  unsigned short* ws = (unsigned short*)d_ws;
  unsigned short* wb   = ws;
  unsigned short* wqkb = wb;
  unsigned short* wvb  = wb + 2097152;
  unsigned short* wob  = wb + 3145728;
  unsigned short* w1b  = wb + 4194304;
  unsigned short* w2b  = wb + 8388608;
  unsigned short* w3b  = wb + 12582912;
  unsigned short* xn   = ws + 16777216;
  unsigned short* qb   = ws + 20971520;
  unsigned short* kb   = ws + 25165824;   // must be qb + 4194304
  unsigned short* vb   = ws + 29360128;   // V^T [bh][64][2048]
  unsigned short* cx   = ws + 33554432;
  unsigned short* gb   = ws + 37748736;
  float* part          = (float*)(ws + 20971520);  // aliases qb..gb (dead by w2)
  unsigned short* hb   = ws + 54525952;

  CvtArgs ca;
  ca.src[0] = q_w; ca.src[1] = k_w; ca.src[2] = v_w; ca.src[3] = o_w;
  ca.src[4] = w1;  ca.src[5] = w2;  ca.src[6] = w3;
  ca.cum[0] = 0;        ca.cum[1] = 1048576;  ca.cum[2] = 2097152;  ca.cum[3] = 3145728;
  ca.cum[4] = 4194304;  ca.cum[5] = 8388608;  ca.cum[6] = 12582912; ca.cum[7] = 16777216;
  cvt_all<<<16384, 256, 0, stream>>>(ca, wb);

  rmsnorm_k<<<4096, 256, 0, stream>>>(in_f, ln1, xn);

  gemm8_qkv<<<192, 512, 0, stream>>>(xn, wqkb, wvb, qb, vb);

  rope2_k<<<8192, 256, 0, stream>>>(qb, kb, pos);

  attn_k<<<1024, 256, 0, stream>>>(qb, kb, vb, cx);

  gemm_res<1024><<<dim3(32, 8), 256, 0, stream>>>(cx, wob, out, in_f);

  rmsnorm_k<<<4096, 256, 0, stream>>>(out, ln2, xn);

  gemm8_k<3><<<256, 512, 0, stream>>>(xn, 1024, w1b, 1024, 16, 0, 16, gb, nullptr, nullptr, nullptr);
  gemm8_k<4><<<256, 512, 0, stream>>>(xn, 1024, w3b, 1024, 16, 0, 16, hb, nullptr, nullptr, gb);
  gemm8_k<5><<<dim3(64, 4), 512, 0, stream>>>(hb, 4096, w2b, 4096, 16, 1024, 16, nullptr, part, nullptr, nullptr);

  reduce_k<<<4096, 256, 0, stream>>>(out, part);
}

// Round 10
// 282.224 us; speedup vs baseline: 1.1126x; 1.0049x over previous
//
#include <hip/hip_runtime.h>
#include <hip/hip_bf16.h>

typedef __attribute__((ext_vector_type(8))) __bf16 bf16x8;
typedef __attribute__((ext_vector_type(4))) float f32x4;

#define DEV static __device__ __forceinline__

DEV unsigned short f2bf(float f) {
  __bf16 h = (__bf16)f;
  union { __bf16 h; unsigned short u; } v; v.h = h;
  return v.u;
}
DEV float bf2f(unsigned short h) {
  union { unsigned int u; float f; } v; v.u = ((unsigned int)h) << 16;
  return v.f;
}
DEV unsigned pkbf(float lo, float hi) {
  union { __bf16 h[2]; unsigned u; } v;
  v.h[0] = (__bf16)lo; v.h[1] = (__bf16)hi;
  return v.u;
}
DEV f32x4 mfma16(bf16x8 a, bf16x8 b, f32x4 c) {
  return __builtin_amdgcn_mfma_f32_16x16x32_bf16(a, b, c, 0, 0, 0);
}
DEV void gload_lds16(const void* g, void* l) {
  __builtin_amdgcn_global_load_lds((__attribute__((address_space(1))) void*)g,
                                   (__attribute__((address_space(3))) void*)l,
                                   16, 0, 0);
}
DEV float fexp2(float x) { return exp2f(x); }

// ---------------- fused f32 -> bf16 convert of all 7 weights ----------------
// regions: 0 q_w 1 k_w 2 v_w 3 o_w 4 w2 (linear) | 5 w1, 6 w3 (row-interleaved into w13)
struct CvtArgs { const float* src[7]; int cum[8]; };
__global__ __launch_bounds__(256) void cvt_all(CvtArgs a, unsigned short* __restrict__ dst) {
  int i = (blockIdx.x * 256 + threadIdx.x) * 4;
  if (i >= a.cum[7]) return;
  int w = 0;
#pragma unroll 7
  for (int t = 0; t < 7; ++t) if (i >= a.cum[t + 1]) w = t + 1;
  int local = i - a.cum[w];
  int di;
  if (w == 5)      di = 8388608 + ((local >> 10) << 11) + (local & 1023);          // w1 -> row 2f
  else if (w == 6) di = 8388608 + ((local >> 10) << 11) + 1024 + (local & 1023);   // w3 -> row 2f+1
  else             di = i;
  float4 v = *(const float4*)(a.src[w] + local);
  dst[di + 0] = f2bf(v.x);
  dst[di + 1] = f2bf(v.y);
  dst[di + 2] = f2bf(v.z);
  dst[di + 3] = f2bf(v.w);
}

// ---------------- RMSNorm: fp32 in -> bf16 out (D=1024) ----------------
__global__ __launch_bounds__(256) void rmsnorm_k(const float* __restrict__ x,
                                                 const float* __restrict__ w,
                                                 unsigned short* __restrict__ out) {
  int row = blockIdx.x;
  int tid = threadIdx.x;
  const float* xr = x + (size_t)row * 1024;
  float4 v = *(const float4*)(xr + tid * 4);
  float ss = v.x * v.x + v.y * v.y + v.z * v.z + v.w * v.w;
#pragma unroll
  for (int m = 32; m >= 1; m >>= 1) ss += __shfl_xor(ss, m);
  __shared__ float red[4];
  int wid = tid >> 6;
  if ((tid & 63) == 0) red[wid] = ss;
  __syncthreads();
  float tot = red[0] + red[1] + red[2] + red[3];
  float rs = rsqrtf(tot * (1.0f / 1024.0f) + 1e-5f);
  float4 wv = *(const float4*)(w + tid * 4);
  unsigned short* o = out + (size_t)row * 1024 + tid * 4;
  o[0] = f2bf(v.x * rs * wv.x);
  o[1] = f2bf(v.y * rs * wv.y);
  o[2] = f2bf(v.z * rs * wv.z);
  o[3] = f2bf(v.w * rs * wv.w);
}

// ---------------- RoPE in-place: one thread rotates q AND k ----------------
__global__ __launch_bounds__(256) void rope2_k(unsigned short* __restrict__ q,
                                               unsigned short* __restrict__ k,
                                               const int* __restrict__ pos) {
  int idx = blockIdx.x * 256 + threadIdx.x;  // 2,097,152 threads
  int i = idx & 31;
  int s = (idx >> 5) & 2047;
  int bh = idx >> 16;
  int b = bh >> 4;
  float p = (float)pos[b * 2048 + s];
  float inv = exp2f(-(float)i * 0.4152410118609203f);
  float ang = p * inv;
  float sn = sinf(ang), cs = cosf(ang);
  size_t base = (((size_t)bh * 2048) + s) * 64 + 2 * i;
  float q1 = bf2f(q[base]), q2 = bf2f(q[base + 1]);
  q[base]     = f2bf(q1 * cs - q2 * sn);
  q[base + 1] = f2bf(q1 * sn + q2 * cs);
  float k1 = bf2f(k[base]), k2 = bf2f(k[base + 1]);
  k[base]     = f2bf(k1 * cs - k2 * sn);
  k[base + 1] = f2bf(k1 * sn + k2 * cs);
}

// ================= 256x256 8-phase GEMM =================
// MODE 0: QK scatter; MODE 1: V^T scatter; MODE 2: fp32 resid add;
// MODE 5: bf16 partial (outb pre-offset by z); MODE 6: fused SwiGLU (N=8192 interleaved)
template <int MODE>
DEV void gemm8_body(const unsigned short* __restrict__ A, int lda,
                    const unsigned short* __restrict__ B, int ldb,
                    int bm, int bn, int kbase, int nt,
                    unsigned short* __restrict__ outb, float* __restrict__ outf,
                    const float* __restrict__ resid,
                    unsigned short* As, unsigned short* Bs) {
  const int tid = threadIdx.x;
  const int lane = tid & 63, wid = tid >> 6;
  const int wr = wid >> 2, wc = wid & 3;
  const int m0 = bm * 256, n0 = bn * 256;

  const int r0 = tid >> 2, r1 = 128 + (tid >> 2), cc = tid & 3;
  const int sc0 = (cc ^ ((r0 >> 1) & 3)) * 8;
  const int sc1 = (cc ^ ((r1 >> 1) & 3)) * 8;
  const size_t arow0 = (size_t)(m0 + r0) * lda, arow1 = (size_t)(m0 + r1) * lda;
  const size_t brow0 = (size_t)(n0 + r0) * ldb, brow1 = (size_t)(n0 + r1) * ldb;
  const int du0 = tid * 8, du1 = (512 + tid) * 8;

  auto stA = [&](int t, int kh) {
    unsigned short* d = As + ((((t & 1) << 1) | kh) * 8192);
    const unsigned short* s = A + kbase + t * 64 + kh * 32;
    gload_lds16(s + arow0 + sc0, d + du0);
    gload_lds16(s + arow1 + sc1, d + du1);
  };
  auto stB = [&](int t, int kh) {
    unsigned short* d = Bs + ((((t & 1) << 1) | kh) * 8192);
    const unsigned short* s = B + kbase + t * 64 + kh * 32;
    gload_lds16(s + brow0 + sc0, d + du0);
    gload_lds16(s + brow1 + sc1, d + du1);
  };

  const int fcol = ((lane >> 4) ^ ((lane >> 1) & 3)) * 8;
  const int frow = lane & 15;
  const int abase = (wr * 128 + frow) * 32 + fcol;
  const int bbase = (wc * 64 + frow) * 32 + fcol;

  f32x4 acc[8][4] = {};
  bf16x8 a[4], b[4];

#define LOADA(buf, ks, mh) { const unsigned short* p_ = As + (((buf) << 1) | (ks)) * 8192 + abase + (mh) * 2048; \
  a[0] = *(const bf16x8*)(p_); a[1] = *(const bf16x8*)(p_ + 512); \
  a[2] = *(const bf16x8*)(p_ + 1024); a[3] = *(const bf16x8*)(p_ + 1536); }
#define LOADB(buf, ks) { const unsigned short* p_ = Bs + (((buf) << 1) | (ks)) * 8192 + bbase; \
  b[0] = *(const bf16x8*)(p_); b[1] = *(const bf16x8*)(p_ + 512); \
  b[2] = *(const bf16x8*)(p_ + 1024); b[3] = *(const bf16x8*)(p_ + 1536); }
#define MFMAQ(mh) { _Pragma("unroll") for (int fi = 0; fi < 4; ++fi) \
  _Pragma("unroll") for (int j = 0; j < 4; ++j) \
    acc[(mh) * 4 + fi][j] = mfma16(a[fi], b[j], acc[(mh) * 4 + fi][j]); }
#define LGK0() { asm volatile("s_waitcnt lgkmcnt(0)" ::: "memory"); __builtin_amdgcn_sched_barrier(0); }

  stA(0, 0); stB(0, 0); stA(0, 1); stB(0, 1);
  stA(1, 0); stB(1, 0);
  asm volatile("s_waitcnt vmcnt(4)" ::: "memory");
  __builtin_amdgcn_s_barrier();

  for (int t = 0; t < nt; ++t) {
    const int buf = t & 1;
    LOADA(buf, 0, 0); LOADB(buf, 0);
    if (t + 1 < nt) stA(t + 1, 1);
    __builtin_amdgcn_s_barrier();
    LGK0();
    __builtin_amdgcn_s_setprio(1); MFMAQ(0); __builtin_amdgcn_s_setprio(0);
    __builtin_amdgcn_s_barrier();
    LOADA(buf, 0, 1);
    if (t + 1 < nt) stB(t + 1, 1);
    __builtin_amdgcn_s_barrier();
    LGK0();
    __builtin_amdgcn_s_setprio(1); MFMAQ(1); __builtin_amdgcn_s_setprio(0);
    __builtin_amdgcn_s_barrier();
    LOADA(buf, 1, 0); LOADB(buf, 1);
    if (t + 2 < nt) stA(t + 2, 0);
    __builtin_amdgcn_s_barrier();
    LGK0();
    __builtin_amdgcn_s_setprio(1); MFMAQ(0); __builtin_amdgcn_s_setprio(0);
    __builtin_amdgcn_s_barrier();
    LOADA(buf, 1, 1);
    if (t + 2 < nt) stB(t + 2, 0);
    __builtin_amdgcn_s_barrier();
    LGK0();
    __builtin_amdgcn_s_setprio(1); MFMAQ(1); __builtin_amdgcn_s_setprio(0);
    if (t + 1 < nt) {
      if (t + 2 < nt) { asm volatile("s_waitcnt vmcnt(4)" ::: "memory"); }
      else            { asm volatile("s_waitcnt vmcnt(0)" ::: "memory"); }
      __builtin_amdgcn_s_barrier();
    }
  }
#undef LOADA
#undef LOADB
#undef MFMAQ
#undef LGK0

#pragma unroll
  for (int i = 0; i < 8; ++i)
#pragma unroll
    for (int j = 0; j < 4; ++j)
#pragma unroll
      for (int r = 0; r < 4; ++r) {
        int m = m0 + wr * 128 + i * 16 + ((lane >> 4) << 2) + r;
        int n = n0 + wc * 64 + j * 16 + (lane & 15);
        float v = acc[i][j][r];
        if (MODE == 0) {
          unsigned short* dst = outb + ((n >= 1024) ? 4194304 : 0);
          int nn = n & 1023;
          int bb = m >> 11, s = m & 2047, hh = nn >> 6, dd = nn & 63;
          dst[(((size_t)bb * 16 + hh) * 2048 + s) * 64 + dd] = f2bf(v);
        } else if (MODE == 1) {
          int hh = m >> 6, dd = m & 63, bb = n >> 11, s = n & 2047;
          outb[(((size_t)bb * 16 + hh) * 64 + dd) * 2048 + s] = f2bf(v);
        } else if (MODE == 2) {
          size_t idx = (size_t)m * 1024 + n;
          outf[idx] = resid[idx] + v;
        } else if (MODE == 5) {
          outb[(size_t)m * 1024 + n] = f2bf(v);
        } else {  // MODE 6: fused SwiGLU; even lane=g(w1 row), odd lane=u(w3 row)
          float other = __shfl_xor(v, 1);
          if (!(lane & 1)) {
            float hv = v / (1.0f + __expf(-v)) * other;
            outb[(size_t)m * 4096 + (n >> 1)] = f2bf(hv);
          }
        }
      }
}

DEV void swz_map(int bid, int nwg, int MT, int& bm, int& bn) {
  int cpx = nwg >> 3;
  int sw = (bid & 7) * cpx + (bid >> 3);
  bm = sw % MT;
  bn = sw / MT;
}

template <int MODE>
__global__ __launch_bounds__(512, 2) void gemm8_k(const unsigned short* __restrict__ A, int lda,
                                                  const unsigned short* __restrict__ B, int ldb,
                                                  int MT, int kz, int nt,
                                                  unsigned short* __restrict__ outb,
                                                  float* __restrict__ outf,
                                                  const float* __restrict__ resid) {
  __shared__ __align__(16) unsigned short lds[65536];
  int bm, bn;
  swz_map(blockIdx.x, gridDim.x, MT, bm, bn);
  int kb = kz * blockIdx.y;
  unsigned short* ob = outb;
  if (MODE == 5) ob += (size_t)blockIdx.y * 4194304;
  gemm8_body<MODE>(A, lda, B, ldb, bm, bn, kb, nt, ob, outf, resid, lds, lds + 32768);
}

__global__ __launch_bounds__(512, 2) void gemm8_qkv(const unsigned short* __restrict__ xn,
                                                    const unsigned short* __restrict__ wqk,
                                                    const unsigned short* __restrict__ wv,
                                                    unsigned short* __restrict__ qk_out,
                                                    unsigned short* __restrict__ vt_out) {
  __shared__ __align__(16) unsigned short lds[65536];
  int bid = blockIdx.x;
  if (bid < 128) {
    int bm, bn;
    swz_map(bid, 128, 16, bm, bn);
    gemm8_body<0>(xn, 1024, wqk, 1024, bm, bn, 0, 16, qk_out, nullptr, nullptr, lds, lds + 32768);
  } else {
    bid -= 128;
    int bm, bn;
    swz_map(bid, 64, 4, bm, bn);
    gemm8_body<1>(wv, 1024, xn, 1024, bm, bn, 0, 16, vt_out, nullptr, nullptr, lds, lds + 32768);
  }
}

// ---------------- 128x128 2-phase GEMM, fp32 out = resid + acc (N=1024) ----------------
template <int K>
__global__ __launch_bounds__(256) void gemm_res(const unsigned short* __restrict__ A,
                                                const unsigned short* __restrict__ Bw,
                                                float* __restrict__ outf,
                                                const float* __restrict__ resid) {
  __shared__ __align__(16) unsigned short As[128 * 64];
  __shared__ __align__(16) unsigned short Bs[128 * 64];
  const int N = 1024;
  const int tid = threadIdx.x;
  const int wid = tid >> 6, lane = tid & 63;
  const int wr = wid >> 1, wc = wid & 1;
  const int m0 = blockIdx.x * 128, n0 = blockIdx.y * 128;
  const int sw = (lane & 7) * 8;
  f32x4 acc[4][4] = {};

  for (int k0 = 0; k0 < K; k0 += 64) {
    __syncthreads();
#pragma unroll
    for (int it = 0; it < 4; ++it) {
      int c = wid * 4 + it;
      int row = c * 8 + (lane >> 3);
      int col = ((lane & 7) ^ (row & 7)) * 8;
      gload_lds16(A + (size_t)(m0 + row) * K + k0 + col, As + c * 512);
      gload_lds16(Bw + (size_t)(n0 + row) * K + k0 + col, Bs + c * 512);
    }
    asm volatile("s_waitcnt vmcnt(0)" ::: "memory");
    __syncthreads();
#pragma unroll
    for (int kk = 0; kk < 2; ++kk) {
      const int kof = (kk * 32 + (lane >> 4) * 8) ^ sw;
      bf16x8 af[4], bfr[4];
#pragma unroll
      for (int i = 0; i < 4; ++i) {
        af[i]  = *(const bf16x8*)(As + (wr * 64 + i * 16 + (lane & 15)) * 64 + kof);
        bfr[i] = *(const bf16x8*)(Bs + (wc * 64 + i * 16 + (lane & 15)) * 64 + kof);
      }
#pragma unroll
      for (int i = 0; i < 4; ++i)
#pragma unroll
        for (int j = 0; j < 4; ++j) acc[i][j] = mfma16(af[i], bfr[j], acc[i][j]);
    }
  }
  const int rb = m0 + wr * 64 + ((lane >> 4) * 4);
  const int cb = n0 + wc * 64 + (lane & 15);
#pragma unroll
  for (int i = 0; i < 4; ++i)
#pragma unroll
    for (int r = 0; r < 4; ++r) {
      int m = rb + i * 16 + r;
#pragma unroll
      for (int j = 0; j < 4; ++j) {
        size_t idx = (size_t)m * N + cb + j * 16;
        outf[idx] = resid[idx] + acc[i][j][r];
      }
    }
}

// ---------------- w2 split-K reduce (bf16 partials) ----------------
__global__ __launch_bounds__(256) void reduce_k(float* __restrict__ out,
                                                const unsigned short* __restrict__ partb) {
  int i = (blockIdx.x * 256 + threadIdx.x) * 4;
  float4 o = *(const float4*)(out + i);
#pragma unroll
  for (int s = 0; s < 4; ++s) {
    uint2 w = *(const uint2*)(partb + (size_t)s * 4194304 + i);
    o.x += bf2f((unsigned short)(w.x & 0xffff));
    o.y += bf2f((unsigned short)(w.x >> 16));
    o.z += bf2f((unsigned short)(w.y & 0xffff));
    o.w += bf2f((unsigned short)(w.y >> 16));
  }
  *(float4*)(out + i) = o;
}

// ---------------- Flash attention: swapped-QK 16x16, dbuf, in-reg softmax ----------------
__global__ __launch_bounds__(256) void attn_k(const unsigned short* __restrict__ q,
                                              const unsigned short* __restrict__ k,
                                              const unsigned short* __restrict__ vt,
                                              unsigned short* __restrict__ ctx) {
  __shared__ __align__(16) unsigned short Ks[2][4096];
  __shared__ __align__(16) unsigned short Vs[2][4096];
  __shared__ __align__(16) unsigned short Ps[4][16 * 72];
  const int bid = blockIdx.x;                       // 1024 blocks
  const int bh = (bid & 7) * 4 + ((bid >> 3) & 3);  // XCD-pinned: 4 heads/XCD
  const int qt = 31 - (bid >> 5);                   // longest first
  const int tid = threadIdx.x, wid = tid >> 6, lane = tid & 63;
  const size_t bhS = (size_t)bh * 2048;
  const size_t bhD = (size_t)bh * 64 * 2048;
  const int b = bh >> 4, hh = bh & 15;
  const int sw = (lane & 7) * 8;
  const int h4 = lane >> 4, l15 = lane & 15;
  const float SC2 = 0.18033688011112042f;  // 0.125 * log2(e)

  const int c0 = wid * 2, c1 = wid * 2 + 1;
  const int row0 = c0 * 8 + (lane >> 3), row1 = c1 * 8 + (lane >> 3);
  const int col0 = ((lane & 7) ^ (row0 & 7)) * 8;
  const int col1 = ((lane & 7) ^ (row1 & 7)) * 8;

  auto stage = [&](int kt, int buf) {
    gload_lds16(k + (bhS + kt * 64 + row0) * 64 + col0, &Ks[buf][c0 * 512]);
    gload_lds16(k + (bhS + kt * 64 + row1) * 64 + col1, &Ks[buf][c1 * 512]);
    gload_lds16(vt + bhD + (size_t)row0 * 2048 + kt * 64 + col0, &Vs[buf][c0 * 512]);
    gload_lds16(vt + bhD + (size_t)row1 * 2048 + kt * 64 + col1, &Vs[buf][c1 * 512]);
  };

  const int q0 = qt * 64;
  bf16x8 qf[2];
  {
    const unsigned short* qp = q + (bhS + q0 + wid * 16 + l15) * 64 + h4 * 8;
    qf[0] = *(const bf16x8*)qp;
    qf[1] = *(const bf16x8*)(qp + 32);
#pragma unroll
    for (int jj = 0; jj < 8; ++jj) {
      qf[0][jj] = (__bf16)((float)qf[0][jj] * SC2);
      qf[1][jj] = (__bf16)((float)qf[1][jj] * SC2);
    }
  }
  float mrow = -1e30f, lrow = 0.0f;
  f32x4 o[4] = {};
  const int qg = q0 + wid * 16 + l15;          // lane's own q (S column)
  const int rowb = q0 + wid * 16 + (h4 << 2);  // output q rows

  stage(0, 0);
  if (qt > 0) { stage(1, 1); asm volatile("s_waitcnt vmcnt(4)" ::: "memory"); }
  else        {              asm volatile("s_waitcnt vmcnt(0)" ::: "memory"); }
  __builtin_amdgcn_s_barrier();

  for (int kt = 0; kt <= qt; ++kt) {
    const int cur = kt & 1;
    float s[16];
#pragma unroll
    for (int nt = 0; nt < 4; ++nt) {
      f32x4 z = {};
#pragma unroll
      for (int ks = 0; ks < 2; ++ks) {
        int kof = (ks * 32 + h4 * 8) ^ sw;
        bf16x8 kf = *(const bf16x8*)(&Ks[cur][(nt * 16 + l15) * 64 + kof]);
        z = mfma16(kf, qf[ks], z);
      }
      s[nt * 4 + 0] = z[0]; s[nt * 4 + 1] = z[1];
      s[nt * 4 + 2] = z[2]; s[nt * 4 + 3] = z[3];
    }
    if (kt == qt) {
#pragma unroll
      for (int nt = 0; nt < 4; ++nt)
#pragma unroll
        for (int r = 0; r < 4; ++r) {
          int key = q0 + nt * 16 + (h4 << 2) + r;
          if (key > qg) s[nt * 4 + r] = -3e38f;
        }
    }
    float pmax = s[0];
#pragma unroll
    for (int i = 1; i < 16; ++i) pmax = fmaxf(pmax, s[i]);
    pmax = fmaxf(pmax, __shfl_xor(pmax, 16));
    pmax = fmaxf(pmax, __shfl_xor(pmax, 32));
    if (!__all(pmax <= mrow + 11.5f)) {
      float mnew = fmaxf(mrow, pmax);
      float dl = mrow - mnew;
      mrow = mnew;
      lrow *= fexp2(dl);
#pragma unroll
      for (int r = 0; r < 4; ++r) {
        float ar = fexp2(__shfl(dl, (h4 << 2) + r, 16));
#pragma unroll
        for (int d = 0; d < 4; ++d) o[d][r] *= ar;
      }
    }
    float sum = 0.0f;
#pragma unroll
    for (int i = 0; i < 16; ++i) { s[i] = fexp2(s[i] - mrow); sum += s[i]; }
    lrow += sum;
    {
      unsigned short* pr = &Ps[wid][l15 * 72 + (h4 << 2)];
#pragma unroll
      for (int nt = 0; nt < 4; ++nt) {
        uint2 w;
        w.x = pkbf(s[4 * nt], s[4 * nt + 1]);
        w.y = pkbf(s[4 * nt + 2], s[4 * nt + 3]);
        *(uint2*)(pr + nt * 16) = w;
      }
    }
#pragma unroll
    for (int ks = 0; ks < 2; ++ks) {
      bf16x8 pf = *(const bf16x8*)(&Ps[wid][l15 * 72 + ks * 32 + (h4 << 3)]);
      int kof = (ks * 32 + h4 * 8) ^ sw;
#pragma unroll
      for (int d = 0; d < 4; ++d) {
        bf16x8 vf = *(const bf16x8*)(&Vs[cur][(d * 16 + l15) * 64 + kof]);
        o[d] = mfma16(pf, vf, o[d]);
      }
    }
    __builtin_amdgcn_s_barrier();
    if (kt + 2 <= qt) {
      stage(kt + 2, cur);
      asm volatile("s_waitcnt vmcnt(4)" ::: "memory");
    } else if (kt + 1 <= qt) {
      asm volatile("s_waitcnt vmcnt(0)" ::: "memory");
    }
    __builtin_amdgcn_s_barrier();
  }
  lrow += __shfl_xor(lrow, 16);
  lrow += __shfl_xor(lrow, 32);
  float inv = 1.0f / lrow;
#pragma unroll
  for (int r = 0; r < 4; ++r) {
    float invr = __shfl(inv, (h4 << 2) + r, 16);
#pragma unroll
    for (int d = 0; d < 4; ++d)
      ctx[((size_t)b * 2048 + (rowb + r)) * 1024 + hh * 64 + d * 16 + l15] = f2bf(o[d][r] * invr);
  }
}

extern "C" void kernel_launch(void* const* d_in, const int* in_sizes, int n_in,
                              void* d_out, int out_size, void* d_ws, size_t ws_size,
                              hipStream_t stream) {
  (void)in_sizes; (void)n_in; (void)out_size; (void)ws_size;
  const float* in_f = (const float*)d_in[0];
  const int* pos    = (const int*)d_in[1];
  const float* q_w  = (const float*)d_in[2];
  const float* k_w  = (const float*)d_in[3];
  const float* v_w  = (const float*)d_in[4];
  const float* o_w  = (const float*)d_in[5];
  const float* ln1  = (const float*)d_in[6];
  const float* ln2  = (const float*)d_in[7];
  const float* w1   = (const float*)d_in[8];
  const float* w2   = (const float*)d_in[9];
  const float* w3   = (const float*)d_in[10];
  float* out = (float*)d_out;

  unsigned short* ws = (unsigned short*)d_ws;
  unsigned short* wb   = ws;
  unsigned short* wqkb = wb;                // 2M
  unsigned short* wvb  = wb + 2097152;      // 1M
  unsigned short* wob  = wb + 3145728;      // 1M
  unsigned short* w2b  = wb + 4194304;      // 4M
  unsigned short* w13b = wb + 8388608;      // 8M (row-interleaved w1/w3)
  unsigned short* xn   = ws + 16777216;
  unsigned short* qb   = ws + 20971520;
  unsigned short* kb   = ws + 25165824;     // must be qb + 4194304
  unsigned short* vb   = ws + 29360128;     // V^T [bh][64][2048]
  unsigned short* cx   = ws + 33554432;
  unsigned short* partb = ws + 20971520;    // 16M u16 bf16 partials, aliases qb..cx (dead by w2)
  unsigned short* hb   = ws + 54525952;

  CvtArgs ca;
  ca.src[0] = q_w; ca.src[1] = k_w; ca.src[2] = v_w; ca.src[3] = o_w;
  ca.src[4] = w2;  ca.src[5] = w1;  ca.src[6] = w3;
  ca.cum[0] = 0;        ca.cum[1] = 1048576;  ca.cum[2] = 2097152;  ca.cum[3] = 3145728;
  ca.cum[4] = 4194304;  ca.cum[5] = 8388608;  ca.cum[6] = 12582912; ca.cum[7] = 16777216;
  cvt_all<<<16384, 256, 0, stream>>>(ca, wb);

  rmsnorm_k<<<4096, 256, 0, stream>>>(in_f, ln1, xn);

  gemm8_qkv<<<192, 512, 0, stream>>>(xn, wqkb, wvb, qb, vb);

  rope2_k<<<8192, 256, 0, stream>>>(qb, kb, pos);

  attn_k<<<1024, 256, 0, stream>>>(qb, kb, vb, cx);

  gemm_res<1024><<<dim3(32, 8), 256, 0, stream>>>(cx, wob, out, in_f);

  rmsnorm_k<<<4096, 256, 0, stream>>>(out, ln2, xn);

  // fused w1+w3 SwiGLU: N=8192 over interleaved weights -> hb bf16 [4096][4096]
  gemm8_k<6><<<512, 512, 0, stream>>>(xn, 1024, w13b, 1024, 16, 0, 16, hb, nullptr, nullptr);

  // w2 split-K=4, bf16 partials
  gemm8_k<5><<<dim3(64, 4), 512, 0, stream>>>(hb, 4096, w2b, 4096, 16, 1024, 16, partb, nullptr, nullptr);

  reduce_k<<<4096, 256, 0, stream>>>(out, partb);
}

// Round 11
// 281.704 us; speedup vs baseline: 1.1147x; 1.0018x over previous
//
#include <hip/hip_runtime.h>
#include <hip/hip_bf16.h>

typedef __attribute__((ext_vector_type(8))) __bf16 bf16x8;
typedef __attribute__((ext_vector_type(4))) float f32x4;

#define DEV static __device__ __forceinline__

DEV unsigned short f2bf(float f) {
  __bf16 h = (__bf16)f;
  union { __bf16 h; unsigned short u; } v; v.h = h;
  return v.u;
}
DEV float bf2f(unsigned short h) {
  union { unsigned int u; float f; } v; v.u = ((unsigned int)h) << 16;
  return v.f;
}
DEV unsigned pkbf(float lo, float hi) {
  union { __bf16 h[2]; unsigned u; } v;
  v.h[0] = (__bf16)lo; v.h[1] = (__bf16)hi;
  return v.u;
}
DEV f32x4 mfma16(bf16x8 a, bf16x8 b, f32x4 c) {
  return __builtin_amdgcn_mfma_f32_16x16x32_bf16(a, b, c, 0, 0, 0);
}
DEV void gload_lds16(const void* g, void* l) {
  __builtin_amdgcn_global_load_lds((__attribute__((address_space(1))) void*)g,
                                   (__attribute__((address_space(3))) void*)l,
                                   16, 0, 0);
}
DEV float fexp2(float x) { return exp2f(x); }

// ---------------- fused f32 -> bf16 convert of all 7 weights ----------------
// regions: 0 q_w 1 k_w 2 v_w 3 o_w 4 w2 (linear) | 5 w1, 6 w3 (row-interleaved into w13)
struct CvtArgs { const float* src[7]; int cum[8]; };
__global__ __launch_bounds__(256) void cvt_all(CvtArgs a, unsigned short* __restrict__ dst) {
  int i = (blockIdx.x * 256 + threadIdx.x) * 4;
  if (i >= a.cum[7]) return;
  int w = 0;
#pragma unroll 7
  for (int t = 0; t < 7; ++t) if (i >= a.cum[t + 1]) w = t + 1;
  int local = i - a.cum[w];
  int di;
  if (w == 5)      di = 8388608 + ((local >> 10) << 11) + (local & 1023);          // w1 -> row 2f
  else if (w == 6) di = 8388608 + ((local >> 10) << 11) + 1024 + (local & 1023);   // w3 -> row 2f+1
  else             di = i;
  float4 v = *(const float4*)(a.src[w] + local);
  dst[di + 0] = f2bf(v.x);
  dst[di + 1] = f2bf(v.y);
  dst[di + 2] = f2bf(v.z);
  dst[di + 3] = f2bf(v.w);
}

// ---------------- RMSNorm: fp32 in -> bf16 out (D=1024) ----------------
__global__ __launch_bounds__(256) void rmsnorm_k(const float* __restrict__ x,
                                                 const float* __restrict__ w,
                                                 unsigned short* __restrict__ out) {
  int row = blockIdx.x;
  int tid = threadIdx.x;
  const float* xr = x + (size_t)row * 1024;
  float4 v = *(const float4*)(xr + tid * 4);
  float ss = v.x * v.x + v.y * v.y + v.z * v.z + v.w * v.w;
#pragma unroll
  for (int m = 32; m >= 1; m >>= 1) ss += __shfl_xor(ss, m);
  __shared__ float red[4];
  int wid = tid >> 6;
  if ((tid & 63) == 0) red[wid] = ss;
  __syncthreads();
  float tot = red[0] + red[1] + red[2] + red[3];
  float rs = rsqrtf(tot * (1.0f / 1024.0f) + 1e-5f);
  float4 wv = *(const float4*)(w + tid * 4);
  unsigned short* o = out + (size_t)row * 1024 + tid * 4;
  o[0] = f2bf(v.x * rs * wv.x);
  o[1] = f2bf(v.y * rs * wv.y);
  o[2] = f2bf(v.z * rs * wv.z);
  o[3] = f2bf(v.w * rs * wv.w);
}

// ---------------- RoPE in-place: one thread rotates q AND k ----------------
__global__ __launch_bounds__(256) void rope2_k(unsigned short* __restrict__ q,
                                               unsigned short* __restrict__ k,
                                               const int* __restrict__ pos) {
  int idx = blockIdx.x * 256 + threadIdx.x;  // 2,097,152 threads
  int i = idx & 31;
  int s = (idx >> 5) & 2047;
  int bh = idx >> 16;
  int b = bh >> 4;
  float p = (float)pos[b * 2048 + s];
  float inv = exp2f(-(float)i * 0.4152410118609203f);
  float ang = p * inv;
  float sn = sinf(ang), cs = cosf(ang);
  size_t base = (((size_t)bh * 2048) + s) * 64 + 2 * i;
  float q1 = bf2f(q[base]), q2 = bf2f(q[base + 1]);
  q[base]     = f2bf(q1 * cs - q2 * sn);
  q[base + 1] = f2bf(q1 * sn + q2 * cs);
  float k1 = bf2f(k[base]), k2 = bf2f(k[base + 1]);
  k[base]     = f2bf(k1 * cs - k2 * sn);
  k[base + 1] = f2bf(k1 * sn + k2 * cs);
}

// ================= 256x256 8-phase GEMM =================
// MODE 0: QK scatter; MODE 1: V^T scatter; MODE 2: fp32 resid add;
// MODE 5: bf16 partial (outb pre-offset by z); MODE 6: fused SwiGLU (N=8192 interleaved)
template <int MODE>
DEV void gemm8_body(const unsigned short* __restrict__ A, int lda,
                    const unsigned short* __restrict__ B, int ldb,
                    int bm, int bn, int kbase, int nt,
                    unsigned short* __restrict__ outb, float* __restrict__ outf,
                    const float* __restrict__ resid,
                    unsigned short* As, unsigned short* Bs) {
  const int tid = threadIdx.x;
  const int lane = tid & 63, wid = tid >> 6;
  const int wr = wid >> 2, wc = wid & 3;
  const int m0 = bm * 256, n0 = bn * 256;

  const int r0 = tid >> 2, r1 = 128 + (tid >> 2), cc = tid & 3;
  const int sc0 = (cc ^ ((r0 >> 1) & 3)) * 8;
  const int sc1 = (cc ^ ((r1 >> 1) & 3)) * 8;
  const size_t arow0 = (size_t)(m0 + r0) * lda, arow1 = (size_t)(m0 + r1) * lda;
  const size_t brow0 = (size_t)(n0 + r0) * ldb, brow1 = (size_t)(n0 + r1) * ldb;
  const int du0 = tid * 8, du1 = (512 + tid) * 8;

  auto stA = [&](int t, int kh) {
    unsigned short* d = As + ((((t & 1) << 1) | kh) * 8192);
    const unsigned short* s = A + kbase + t * 64 + kh * 32;
    gload_lds16(s + arow0 + sc0, d + du0);
    gload_lds16(s + arow1 + sc1, d + du1);
  };
  auto stB = [&](int t, int kh) {
    unsigned short* d = Bs + ((((t & 1) << 1) | kh) * 8192);
    const unsigned short* s = B + kbase + t * 64 + kh * 32;
    gload_lds16(s + brow0 + sc0, d + du0);
    gload_lds16(s + brow1 + sc1, d + du1);
  };

  const int fcol = ((lane >> 4) ^ ((lane >> 1) & 3)) * 8;
  const int frow = lane & 15;
  const int abase = (wr * 128 + frow) * 32 + fcol;
  const int bbase = (wc * 64 + frow) * 32 + fcol;

  f32x4 acc[8][4] = {};
  bf16x8 a[4], b[4];

#define LOADA(buf, ks, mh) { const unsigned short* p_ = As + (((buf) << 1) | (ks)) * 8192 + abase + (mh) * 2048; \
  a[0] = *(const bf16x8*)(p_); a[1] = *(const bf16x8*)(p_ + 512); \
  a[2] = *(const bf16x8*)(p_ + 1024); a[3] = *(const bf16x8*)(p_ + 1536); }
#define LOADB(buf, ks) { const unsigned short* p_ = Bs + (((buf) << 1) | (ks)) * 8192 + bbase; \
  b[0] = *(const bf16x8*)(p_); b[1] = *(const bf16x8*)(p_ + 512); \
  b[2] = *(const bf16x8*)(p_ + 1024); b[3] = *(const bf16x8*)(p_ + 1536); }
#define MFMAQ(mh) { _Pragma("unroll") for (int fi = 0; fi < 4; ++fi) \
  _Pragma("unroll") for (int j = 0; j < 4; ++j) \
    acc[(mh) * 4 + fi][j] = mfma16(a[fi], b[j], acc[(mh) * 4 + fi][j]); }
// NOTE: no sched_barrier(0) here — C++ ds_reads are compiler-tracked; the
// sched_barrier pinned instruction order (m141-class pessimization) and
// blocked next-phase ds_read hoisting under the MFMA cluster.
#define LGK0() { asm volatile("s_waitcnt lgkmcnt(0)" ::: "memory"); }

  stA(0, 0); stB(0, 0); stA(0, 1); stB(0, 1);
  stA(1, 0); stB(1, 0);
  asm volatile("s_waitcnt vmcnt(4)" ::: "memory");
  __builtin_amdgcn_s_barrier();

  for (int t = 0; t < nt; ++t) {
    const int buf = t & 1;
    LOADA(buf, 0, 0); LOADB(buf, 0);
    if (t + 1 < nt) stA(t + 1, 1);
    __builtin_amdgcn_s_barrier();
    LGK0();
    __builtin_amdgcn_s_setprio(1); MFMAQ(0); __builtin_amdgcn_s_setprio(0);
    __builtin_amdgcn_s_barrier();
    LOADA(buf, 0, 1);
    if (t + 1 < nt) stB(t + 1, 1);
    __builtin_amdgcn_s_barrier();
    LGK0();
    __builtin_amdgcn_s_setprio(1); MFMAQ(1); __builtin_amdgcn_s_setprio(0);
    __builtin_amdgcn_s_barrier();
    LOADA(buf, 1, 0); LOADB(buf, 1);
    if (t + 2 < nt) stA(t + 2, 0);
    __builtin_amdgcn_s_barrier();
    LGK0();
    __builtin_amdgcn_s_setprio(1); MFMAQ(0); __builtin_amdgcn_s_setprio(0);
    __builtin_amdgcn_s_barrier();
    LOADA(buf, 1, 1);
    if (t + 2 < nt) stB(t + 2, 0);
    __builtin_amdgcn_s_barrier();
    LGK0();
    __builtin_amdgcn_s_setprio(1); MFMAQ(1); __builtin_amdgcn_s_setprio(0);
    if (t + 1 < nt) {
      if (t + 2 < nt) { asm volatile("s_waitcnt vmcnt(4)" ::: "memory"); }
      else            { asm volatile("s_waitcnt vmcnt(0)" ::: "memory"); }
      __builtin_amdgcn_s_barrier();
    }
  }
#undef LOADA
#undef LOADB
#undef MFMAQ
#undef LGK0

#pragma unroll
  for (int i = 0; i < 8; ++i)
#pragma unroll
    for (int j = 0; j < 4; ++j)
#pragma unroll
      for (int r = 0; r < 4; ++r) {
        int m = m0 + wr * 128 + i * 16 + ((lane >> 4) << 2) + r;
        int n = n0 + wc * 64 + j * 16 + (lane & 15);
        float v = acc[i][j][r];
        if (MODE == 0) {
          unsigned short* dst = outb + ((n >= 1024) ? 4194304 : 0);
          int nn = n & 1023;
          int bb = m >> 11, s = m & 2047, hh = nn >> 6, dd = nn & 63;
          dst[(((size_t)bb * 16 + hh) * 2048 + s) * 64 + dd] = f2bf(v);
        } else if (MODE == 1) {
          int hh = m >> 6, dd = m & 63, bb = n >> 11, s = n & 2047;
          outb[(((size_t)bb * 16 + hh) * 64 + dd) * 2048 + s] = f2bf(v);
        } else if (MODE == 2) {
          size_t idx = (size_t)m * 1024 + n;
          outf[idx] = resid[idx] + v;
        } else if (MODE == 5) {
          outb[(size_t)m * 1024 + n] = f2bf(v);
        } else {  // MODE 6: fused SwiGLU; even lane=g(w1 row), odd lane=u(w3 row)
          float other = __shfl_xor(v, 1);
          if (!(lane & 1)) {
            float hv = v / (1.0f + __expf(-v)) * other;
            outb[(size_t)m * 4096 + (n >> 1)] = f2bf(hv);
          }
        }
      }
}

DEV void swz_map(int bid, int nwg, int MT, int& bm, int& bn) {
  int cpx = nwg >> 3;
  int sw = (bid & 7) * cpx + (bid >> 3);
  bm = sw % MT;
  bn = sw / MT;
}

template <int MODE>
__global__ __launch_bounds__(512, 2) void gemm8_k(const unsigned short* __restrict__ A, int lda,
                                                  const unsigned short* __restrict__ B, int ldb,
                                                  int MT, int kz, int nt,
                                                  unsigned short* __restrict__ outb,
                                                  float* __restrict__ outf,
                                                  const float* __restrict__ resid) {
  __shared__ __align__(16) unsigned short lds[65536];
  int bm, bn;
  swz_map(blockIdx.x, gridDim.x, MT, bm, bn);
  int kb = kz * blockIdx.y;
  unsigned short* ob = outb;
  if (MODE == 5) ob += (size_t)blockIdx.y * 4194304;
  gemm8_body<MODE>(A, lda, B, ldb, bm, bn, kb, nt, ob, outf, resid, lds, lds + 32768);
}

__global__ __launch_bounds__(512, 2) void gemm8_qkv(const unsigned short* __restrict__ xn,
                                                    const unsigned short* __restrict__ wqk,
                                                    const unsigned short* __restrict__ wv,
                                                    unsigned short* __restrict__ qk_out,
                                                    unsigned short* __restrict__ vt_out) {
  __shared__ __align__(16) unsigned short lds[65536];
  int bid = blockIdx.x;
  if (bid < 128) {
    int bm, bn;
    swz_map(bid, 128, 16, bm, bn);
    gemm8_body<0>(xn, 1024, wqk, 1024, bm, bn, 0, 16, qk_out, nullptr, nullptr, lds, lds + 32768);
  } else {
    bid -= 128;
    int bm, bn;
    swz_map(bid, 64, 4, bm, bn);
    gemm8_body<1>(wv, 1024, xn, 1024, bm, bn, 0, 16, vt_out, nullptr, nullptr, lds, lds + 32768);
  }
}

// ---------------- 128x128 2-phase GEMM, fp32 out = resid + acc (N=1024) ----------------
template <int K>
__global__ __launch_bounds__(256) void gemm_res(const unsigned short* __restrict__ A,
                                                const unsigned short* __restrict__ Bw,
                                                float* __restrict__ outf,
                                                const float* __restrict__ resid) {
  __shared__ __align__(16) unsigned short As[128 * 64];
  __shared__ __align__(16) unsigned short Bs[128 * 64];
  const int N = 1024;
  const int tid = threadIdx.x;
  const int wid = tid >> 6, lane = tid & 63;
  const int wr = wid >> 1, wc = wid & 1;
  const int m0 = blockIdx.x * 128, n0 = blockIdx.y * 128;
  const int sw = (lane & 7) * 8;
  f32x4 acc[4][4] = {};

  for (int k0 = 0; k0 < K; k0 += 64) {
    __syncthreads();
#pragma unroll
    for (int it = 0; it < 4; ++it) {
      int c = wid * 4 + it;
      int row = c * 8 + (lane >> 3);
      int col = ((lane & 7) ^ (row & 7)) * 8;
      gload_lds16(A + (size_t)(m0 + row) * K + k0 + col, As + c * 512);
      gload_lds16(Bw + (size_t)(n0 + row) * K + k0 + col, Bs + c * 512);
    }
    asm volatile("s_waitcnt vmcnt(0)" ::: "memory");
    __syncthreads();
#pragma unroll
    for (int kk = 0; kk < 2; ++kk) {
      const int kof = (kk * 32 + (lane >> 4) * 8) ^ sw;
      bf16x8 af[4], bfr[4];
#pragma unroll
      for (int i = 0; i < 4; ++i) {
        af[i]  = *(const bf16x8*)(As + (wr * 64 + i * 16 + (lane & 15)) * 64 + kof);
        bfr[i] = *(const bf16x8*)(Bs + (wc * 64 + i * 16 + (lane & 15)) * 64 + kof);
      }
#pragma unroll
      for (int i = 0; i < 4; ++i)
#pragma unroll
        for (int j = 0; j < 4; ++j) acc[i][j] = mfma16(af[i], bfr[j], acc[i][j]);
    }
  }
  const int rb = m0 + wr * 64 + ((lane >> 4) * 4);
  const int cb = n0 + wc * 64 + (lane & 15);
#pragma unroll
  for (int i = 0; i < 4; ++i)
#pragma unroll
    for (int r = 0; r < 4; ++r) {
      int m = rb + i * 16 + r;
#pragma unroll
      for (int j = 0; j < 4; ++j) {
        size_t idx = (size_t)m * N + cb + j * 16;
        outf[idx] = resid[idx] + acc[i][j][r];
      }
    }
}

// ---------------- w2 split-K reduce (bf16 partials) ----------------
__global__ __launch_bounds__(256) void reduce_k(float* __restrict__ out,
                                                const unsigned short* __restrict__ partb) {
  int i = (blockIdx.x * 256 + threadIdx.x) * 4;
  float4 o = *(const float4*)(out + i);
#pragma unroll
  for (int s = 0; s < 4; ++s) {
    uint2 w = *(const uint2*)(partb + (size_t)s * 4194304 + i);
    o.x += bf2f((unsigned short)(w.x & 0xffff));
    o.y += bf2f((unsigned short)(w.x >> 16));
    o.z += bf2f((unsigned short)(w.y & 0xffff));
    o.w += bf2f((unsigned short)(w.y >> 16));
  }
  *(float4*)(out + i) = o;
}

// ---------------- Flash attention: swapped-QK 16x16, dbuf, in-reg softmax ----------------
__global__ __launch_bounds__(256) void attn_k(const unsigned short* __restrict__ q,
                                              const unsigned short* __restrict__ k,
                                              const unsigned short* __restrict__ vt,
                                              unsigned short* __restrict__ ctx) {
  __shared__ __align__(16) unsigned short Ks[2][4096];
  __shared__ __align__(16) unsigned short Vs[2][4096];
  __shared__ __align__(16) unsigned short Ps[4][16 * 72];
  const int bid = blockIdx.x;                       // 1024 blocks
  const int bh = (bid & 7) * 4 + ((bid >> 3) & 3);  // XCD-pinned: 4 heads/XCD
  const int qt = 31 - (bid >> 5);                   // longest first
  const int tid = threadIdx.x, wid = tid >> 6, lane = tid & 63;
  const size_t bhS = (size_t)bh * 2048;
  const size_t bhD = (size_t)bh * 64 * 2048;
  const int b = bh >> 4, hh = bh & 15;
  const int sw = (lane & 7) * 8;
  const int h4 = lane >> 4, l15 = lane & 15;
  const float SC2 = 0.18033688011112042f;  // 0.125 * log2(e)

  const int c0 = wid * 2, c1 = wid * 2 + 1;
  const int row0 = c0 * 8 + (lane >> 3), row1 = c1 * 8 + (lane >> 3);
  const int col0 = ((lane & 7) ^ (row0 & 7)) * 8;
  const int col1 = ((lane & 7) ^ (row1 & 7)) * 8;

  auto stage = [&](int kt, int buf) {
    gload_lds16(k + (bhS + kt * 64 + row0) * 64 + col0, &Ks[buf][c0 * 512]);
    gload_lds16(k + (bhS + kt * 64 + row1) * 64 + col1, &Ks[buf][c1 * 512]);
    gload_lds16(vt + bhD + (size_t)row0 * 2048 + kt * 64 + col0, &Vs[buf][c0 * 512]);
    gload_lds16(vt + bhD + (size_t)row1 * 2048 + kt * 64 + col1, &Vs[buf][c1 * 512]);
  };

  const int q0 = qt * 64;
  bf16x8 qf[2];
  {
    const unsigned short* qp = q + (bhS + q0 + wid * 16 + l15) * 64 + h4 * 8;
    qf[0] = *(const bf16x8*)qp;
    qf[1] = *(const bf16x8*)(qp + 32);
#pragma unroll
    for (int jj = 0; jj < 8; ++jj) {
      qf[0][jj] = (__bf16)((float)qf[0][jj] * SC2);
      qf[1][jj] = (__bf16)((float)qf[1][jj] * SC2);
    }
  }
  float mrow = -1e30f, lrow = 0.0f;
  f32x4 o[4] = {};
  const int qg = q0 + wid * 16 + l15;          // lane's own q (S column)
  const int rowb = q0 + wid * 16 + (h4 << 2);  // output q rows

  stage(0, 0);
  if (qt > 0) { stage(1, 1); asm volatile("s_waitcnt vmcnt(4)" ::: "memory"); }
  else        {              asm volatile("s_waitcnt vmcnt(0)" ::: "memory"); }
  __builtin_amdgcn_s_barrier();

  for (int kt = 0; kt <= qt; ++kt) {
    const int cur = kt & 1;
    float s[16];
#pragma unroll
    for (int nt = 0; nt < 4; ++nt) {
      f32x4 z = {};
#pragma unroll
      for (int ks = 0; ks < 2; ++ks) {
        int kof = (ks * 32 + h4 * 8) ^ sw;
        bf16x8 kf = *(const bf16x8*)(&Ks[cur][(nt * 16 + l15) * 64 + kof]);
        z = mfma16(kf, qf[ks], z);
      }
      s[nt * 4 + 0] = z[0]; s[nt * 4 + 1] = z[1];
      s[nt * 4 + 2] = z[2]; s[nt * 4 + 3] = z[3];
    }
    if (kt == qt) {
#pragma unroll
      for (int nt = 0; nt < 4; ++nt)
#pragma unroll
        for (int r = 0; r < 4; ++r) {
          int key = q0 + nt * 16 + (h4 << 2) + r;
          if (key > qg) s[nt * 4 + r] = -3e38f;
        }
    }
    float pmax = s[0];
#pragma unroll
    for (int i = 1; i < 16; ++i) pmax = fmaxf(pmax, s[i]);
    pmax = fmaxf(pmax, __shfl_xor(pmax, 16));
    pmax = fmaxf(pmax, __shfl_xor(pmax, 32));
    if (!__all(pmax <= mrow + 11.5f)) {
      float mnew = fmaxf(mrow, pmax);
      float dl = mrow - mnew;
      mrow = mnew;
      lrow *= fexp2(dl);
#pragma unroll
      for (int r = 0; r < 4; ++r) {
        float ar = fexp2(__shfl(dl, (h4 << 2) + r, 16));
#pragma unroll
        for (int d = 0; d < 4; ++d) o[d][r] *= ar;
      }
    }
    float sum = 0.0f;
#pragma unroll
    for (int i = 0; i < 16; ++i) { s[i] = fexp2(s[i] - mrow); sum += s[i]; }
    lrow += sum;
    {
      unsigned short* pr = &Ps[wid][l15 * 72 + (h4 << 2)];
#pragma unroll
      for (int nt = 0; nt < 4; ++nt) {
        uint2 w;
        w.x = pkbf(s[4 * nt], s[4 * nt + 1]);
        w.y = pkbf(s[4 * nt + 2], s[4 * nt + 3]);
        *(uint2*)(pr + nt * 16) = w;
      }
    }
#pragma unroll
    for (int ks = 0; ks < 2; ++ks) {
      bf16x8 pf = *(const bf16x8*)(&Ps[wid][l15 * 72 + ks * 32 + (h4 << 3)]);
      int kof = (ks * 32 + h4 * 8) ^ sw;
#pragma unroll
      for (int d = 0; d < 4; ++d) {
        bf16x8 vf = *(const bf16x8*)(&Vs[cur][(d * 16 + l15) * 64 + kof]);
        o[d] = mfma16(pf, vf, o[d]);
      }
    }
    __builtin_amdgcn_s_barrier();
    if (kt + 2 <= qt) {
      stage(kt + 2, cur);
      asm volatile("s_waitcnt vmcnt(4)" ::: "memory");
    } else if (kt + 1 <= qt) {
      asm volatile("s_waitcnt vmcnt(0)" ::: "memory");
    }
    __builtin_amdgcn_s_barrier();
  }
  lrow += __shfl_xor(lrow, 16);
  lrow += __shfl_xor(lrow, 32);
  float inv = 1.0f / lrow;
#pragma unroll
  for (int r = 0; r < 4; ++r) {
    float invr = __shfl(inv, (h4 << 2) + r, 16);
#pragma unroll
    for (int d = 0; d < 4; ++d)
      ctx[((size_t)b * 2048 + (rowb + r)) * 1024 + hh * 64 + d * 16 + l15] = f2bf(o[d][r] * invr);
  }
}

extern "C" void kernel_launch(void* const* d_in, const int* in_sizes, int n_in,
                              void* d_out, int out_size, void* d_ws, size_t ws_size,
                              hipStream_t stream) {
  (void)in_sizes; (void)n_in; (void)out_size; (void)ws_size;
  const float* in_f = (const float*)d_in[0];
  const int* pos    = (const int*)d_in[1];
  const float* q_w  = (const float*)d_in[2];
  const float* k_w  = (const float*)d_in[3];
  const float* v_w  = (const float*)d_in[4];
  const float* o_w  = (const float*)d_in[5];
  const float* ln1  = (const float*)d_in[6];
  const float* ln2  = (const float*)d_in[7];
  const float* w1   = (const float*)d_in[8];
  const float* w2   = (const float*)d_in[9];
  const float* w3   = (const float*)d_in[10];
  float* out = (float*)d_out;

  unsigned short* ws = (unsigned short*)d_ws;
  unsigned short* wb   = ws;
  unsigned short* wqkb = wb;                // 2M
  unsigned short* wvb  = wb + 2097152;      // 1M
  unsigned short* wob  = wb + 3145728;      // 1M
  unsigned short* w2b  = wb + 4194304;      // 4M
  unsigned short* w13b = wb + 8388608;      // 8M (row-interleaved w1/w3)
  unsigned short* xn   = ws + 16777216;
  unsigned short* qb   = ws + 20971520;
  unsigned short* kb   = ws + 25165824;     // must be qb + 4194304
  unsigned short* vb   = ws + 29360128;     // V^T [bh][64][2048]
  unsigned short* cx   = ws + 33554432;
  unsigned short* partb = ws + 20971520;    // 16M u16 bf16 partials, aliases qb..cx (dead by w2)
  unsigned short* hb   = ws + 54525952;

  CvtArgs ca;
  ca.src[0] = q_w; ca.src[1] = k_w; ca.src[2] = v_w; ca.src[3] = o_w;
  ca.src[4] = w2;  ca.src[5] = w1;  ca.src[6] = w3;
  ca.cum[0] = 0;        ca.cum[1] = 1048576;  ca.cum[2] = 2097152;  ca.cum[3] = 3145728;
  ca.cum[4] = 4194304;  ca.cum[5] = 8388608;  ca.cum[6] = 12582912; ca.cum[7] = 16777216;
  cvt_all<<<16384, 256, 0, stream>>>(ca, wb);

  rmsnorm_k<<<4096, 256, 0, stream>>>(in_f, ln1, xn);

  gemm8_qkv<<<192, 512, 0, stream>>>(xn, wqkb, wvb, qb, vb);

  rope2_k<<<8192, 256, 0, stream>>>(qb, kb, pos);

  attn_k<<<1024, 256, 0, stream>>>(qb, kb, vb, cx);

  gemm_res<1024><<<dim3(32, 8), 256, 0, stream>>>(cx, wob, out, in_f);

  rmsnorm_k<<<4096, 256, 0, stream>>>(out, ln2, xn);

  // fused w1+w3 SwiGLU: N=8192 over interleaved weights -> hb bf16 [4096][4096]
  gemm8_k<6><<<512, 512, 0, stream>>>(xn, 1024, w13b, 1024, 16, 0, 16, hb, nullptr, nullptr);

  // w2 split-K=4, bf16 partials
  gemm8_k<5><<<dim3(64, 4), 512, 0, stream>>>(hb, 4096, w2b, 4096, 16, 1024, 16, partb, nullptr, nullptr);

  reduce_k<<<4096, 256, 0, stream>>>(out, partb);
}